// Round 8
// baseline (323.731 us; speedup 1.0000x reference)
//
#include <hip/hip_runtime.h>
#include <hip/hip_bf16.h>

typedef __bf16 bf16_t;
typedef __bf16 bf16x4 __attribute__((ext_vector_type(4)));
typedef __bf16 bf16x8 __attribute__((ext_vector_type(8)));
typedef float f32x4 __attribute__((ext_vector_type(4)));
typedef unsigned uintx2 __attribute__((ext_vector_type(2)));

#define MFMA16(a, b, c) __builtin_amdgcn_mfma_f32_16x16x32_bf16((a), (b), (c), 0, 0, 0)

#if defined(__has_builtin) && __has_builtin(__builtin_amdgcn_exp2f)
#define EXP2F(x) __builtin_amdgcn_exp2f(x)
#else
#define EXP2F(x) exp2f(x)
#endif

__device__ __forceinline__ void async_copy16(const void* g, void* l) {
#if defined(__has_builtin) && __has_builtin(__builtin_amdgcn_global_load_lds)
  __builtin_amdgcn_global_load_lds((__attribute__((address_space(1))) void*)g,
                                   (__attribute__((address_space(3))) void*)l, 16, 0, 0);
#else
  *(bf16x8*)l = *(const bf16x8*)g;
#endif
}

// tanh-approx GELU in sigmoid form: x*sigmoid(2c(x+0.044715x^3)); |err|<~3e-3
__device__ __forceinline__ float gelu_f(float x) {
  float u = x * (1.5957691216057308f + 0.07135481283f * x * x);
  return x / (1.0f + __expf(-u));
}

// pack two f32 -> one u32 of 2 bf16 (low = lo)
__device__ __forceinline__ unsigned cvt_pk_bf16(float lo, float hi) {
  unsigned r;
  asm("v_cvt_pk_bf16_f32 %0, %1, %2" : "=v"(r) : "v"(lo), "v"(hi));
  return r;
}

// pair swap: a' = {a[0:31], b[0:31]}, b' = {a[32:63], b[32:63]}
__device__ __forceinline__ void plane32_swap(unsigned& a, unsigned& b) {
#if defined(__has_builtin) && __has_builtin(__builtin_amdgcn_permlane32_swap)
  uintx2 r = __builtin_amdgcn_permlane32_swap(a, b, false, false);
  a = r[0];
  b = r[1];
#else
  const int lane = threadIdx.x & 63;
  unsigned as = (unsigned)__shfl_xor((int)a, 32);
  unsigned bs = (unsigned)__shfl_xor((int)b, 32);
  unsigned na = (lane < 32) ? a : bs;
  unsigned nb = (lane < 32) ? as : b;
  a = na;
  b = nb;
#endif
}

// per-16 swap within each half: a' = {a@0,b@0,a@2,b@2}, b' = {a@1,b@1,a@3,b@3}
__device__ __forceinline__ void plane16_swap(unsigned& a, unsigned& b) {
#if defined(__has_builtin) && __has_builtin(__builtin_amdgcn_permlane16_swap)
  uintx2 r = __builtin_amdgcn_permlane16_swap(a, b, false, false);
  a = r[0];
  b = r[1];
#else
  const int lane = threadIdx.x & 63;
  unsigned as = (unsigned)__shfl_xor((int)a, 16);
  unsigned bs = (unsigned)__shfl_xor((int)b, 16);
  unsigned na = (lane & 16) ? bs : a;
  unsigned nb = (lane & 16) ? b : as;
  a = na;
  b = nb;
#endif
}

// ---------------- all weight fp32 -> bf16 converts, ONE dispatch -------------
__global__ __launch_bounds__(256) void cvt_all(const float* __restrict__ sq,
                                               const float* __restrict__ sk,
                                               const float* __restrict__ sv,
                                               const float* __restrict__ so,
                                               const float* __restrict__ s1,
                                               const float* __restrict__ s2,
                                               bf16_t* __restrict__ dq,
                                               bf16_t* __restrict__ dk,
                                               bf16_t* __restrict__ dv,
                                               bf16_t* __restrict__ do_,
                                               bf16_t* __restrict__ d1,
                                               bf16_t* __restrict__ d2) {
  const int y = blockIdx.y;
  const float* s;
  bf16_t* d;
  if (y < 4) {
    s = (y == 0) ? sq : (y == 1) ? sk : (y == 2) ? sv : so;
    d = (y == 0) ? dq : (y == 1) ? dk : (y == 2) ? dv : do_;
  } else if (y < 8) {
    s = s1 + (size_t)(y - 4) * 1048576;
    d = d1 + (size_t)(y - 4) * 1048576;
  } else {
    s = s2 + (size_t)(y - 8) * 1048576;
    d = d2 + (size_t)(y - 8) * 1048576;
  }
  int i = (blockIdx.x * 256 + threadIdx.x) * 4;
  float4 f = *(const float4*)(s + i);
  d[i + 0] = (bf16_t)f.x;
  d[i + 1] = (bf16_t)f.y;
  d[i + 2] = (bf16_t)f.z;
  d[i + 3] = (bf16_t)f.w;
}

// ---------------- layernorm over 1024 cols, one block per row ----------------
__global__ __launch_bounds__(256) void ln_k(const float* __restrict__ x,
                                            const float* __restrict__ g,
                                            const float* __restrict__ b,
                                            bf16_t* __restrict__ o) {
  __shared__ float red[8];
  const int t = threadIdx.x;
  const size_t row = blockIdx.x;
  float4 xv = ((const float4*)(x + row * 1024))[t];
  float s = xv.x + xv.y + xv.z + xv.w;
  float s2 = xv.x * xv.x + xv.y * xv.y + xv.z * xv.z + xv.w * xv.w;
#pragma unroll
  for (int off = 1; off < 64; off <<= 1) {
    s += __shfl_xor(s, off);
    s2 += __shfl_xor(s2, off);
  }
  if ((t & 63) == 0) {
    red[t >> 6] = s;
    red[4 + (t >> 6)] = s2;
  }
  __syncthreads();
  s = red[0] + red[1] + red[2] + red[3];
  s2 = red[4] + red[5] + red[6] + red[7];
  const float mu = s * (1.0f / 1024.0f);
  const float rstd = rsqrtf(s2 * (1.0f / 1024.0f) - mu * mu + 1e-5f);
  float4 gv = ((const float4*)g)[t];
  float4 bv = ((const float4*)b)[t];
  bf16_t* op = o + row * 1024 + t * 4;
  op[0] = (bf16_t)((xv.x - mu) * rstd * gv.x + bv.x);
  op[1] = (bf16_t)((xv.y - mu) * rstd * gv.y + bv.y);
  op[2] = (bf16_t)((xv.z - mu) * rstd * gv.z + bv.z);
  op[3] = (bf16_t)((xv.w - mu) * rstd * gv.w + bv.w);
}

// ---------------- 256x256xBK64 GEMM, slab waves + B-register cache -----------
template <int EPI>
__global__ __launch_bounds__(512, 2) void gemm256(const bf16_t* __restrict__ A,
                                                  const bf16_t* __restrict__ W,
                                                  bf16_t* __restrict__ Cb,
                                                  const float* __restrict__ bias,
                                                  int Nn, int K) {
  __shared__ alignas(16) bf16_t As[2][2 * 128 * 64];
  __shared__ alignas(16) bf16_t Bs[2][2 * 128 * 64];
  const int t = threadIdx.x;
  const int lane = t & 63;
  const int w = t >> 6;
  // bijective XCD swizzle (gridDim.x % 8 == 0)
  const int cpx = gridDim.x >> 3;
  const int bid = blockIdx.x;
  const int swz = (bid & 7) * cpx + (bid >> 3);
  const int nbx = Nn >> 8;
  const int bm = (swz / nbx) * 256;
  const int bn = (swz % nbx) * 256;
  const int wmh = w >> 2;  // A half-tile this wave consumes (rows wmh*128..)
  const int wnq = w & 3;   // 64-col slice
  const int lr = lane & 15;
  const int lq = lane >> 4;
  f32x4 acc[8][4] = {};
  // swizzled ds_read base offsets; frag (i or j) adds i*1024 (16 rows * 64)
  int abase[2], bbase[2];
#pragma unroll
  for (int ks = 0; ks < 2; ++ks) {
    const int sw = ((ks * 4 + lq) ^ (lr & 7)) * 8;
    abase[ks] = wmh * 8192 + lr * 64 + sw;
    bbase[ks] = (wnq >> 1) * 8192 + (wnq & 1) * 4096 + lr * 64 + sw;
  }
  // per-thread staging pointers (pre-swizzled global source), linear LDS dst
  const bf16_t* apt[2][2];
  const bf16_t* bpt[2][2];
  int ldst[2];
#pragma unroll
  for (int c = 0; c < 2; ++c) {
    const int flat = c * 512 + t;        // 16B chunk 0..1023 within a half
    const int r = flat >> 3;             // row within half 0..127
    const int q = (flat & 7) ^ (r & 7);  // pre-swizzled 8-elem slot
    ldst[c] = flat * 8;
#pragma unroll
    for (int h = 0; h < 2; ++h) {
      apt[h][c] = A + (size_t)(bm + h * 128 + r) * K + q * 8;
      bpt[h][c] = W + (size_t)(bn + h * 128 + r) * K + q * 8;
    }
  }
  const int NT = K >> 6;
  // prologue: issue tile 0 stages
#pragma unroll
  for (int c = 0; c < 2; ++c) async_copy16(apt[0][c], &As[0][ldst[c]]);
#pragma unroll
  for (int c = 0; c < 2; ++c) async_copy16(bpt[0][c], &Bs[0][ldst[c]]);
#pragma unroll
  for (int c = 0; c < 2; ++c) async_copy16(bpt[1][c], &Bs[0][8192 + ldst[c]]);
#pragma unroll
  for (int c = 0; c < 2; ++c) async_copy16(apt[1][c], &As[0][8192 + ldst[c]]);
  for (int kt = 0; kt < NT; ++kt) {
    const bf16_t* Ab = As[kt & 1];
    const bf16_t* Bb = Bs[kt & 1];
    bf16_t* Asn = As[(kt & 1) ^ 1];
    bf16_t* Bsn = Bs[(kt & 1) ^ 1];
    const int nk = (kt + 1) << 6;
    if (kt + 1 < NT) {
#pragma unroll
      for (int c = 0; c < 2; ++c) async_copy16(apt[0][c] + nk, Asn + ldst[c]);
#pragma unroll
      for (int c = 0; c < 2; ++c) async_copy16(bpt[0][c] + nk, Bsn + ldst[c]);
#pragma unroll
      for (int c = 0; c < 2; ++c)
        async_copy16(bpt[1][c] + nk, Bsn + 8192 + ldst[c]);
#pragma unroll
      for (int c = 0; c < 2; ++c)
        async_copy16(apt[1][c] + nk, Asn + 8192 + ldst[c]);
      // 8 newest (this tile's stages) may stay in flight; all older retired
      asm volatile("s_waitcnt vmcnt(8)" ::: "memory");
    } else {
      asm volatile("s_waitcnt vmcnt(0)" ::: "memory");
    }
    __builtin_amdgcn_s_barrier();  // buf published to all waves
    // B fragments once per K-tile (held in regs across all 4 phases)
    bf16x8 bfr[4][2];
#pragma unroll
    for (int j = 0; j < 4; ++j)
#pragma unroll
      for (int ks = 0; ks < 2; ++ks)
        bfr[j][ks] = *(const bf16x8*)&Bb[bbase[ks] + j * 1024];
    // 4 phases over the wave's 8 m-frags
#pragma unroll
    for (int p = 0; p < 4; ++p) {
      bf16x8 af[2][2];
#pragma unroll
      for (int ii = 0; ii < 2; ++ii)
#pragma unroll
        for (int ks = 0; ks < 2; ++ks)
          af[ii][ks] = *(const bf16x8*)&Ab[abase[ks] + (p * 2 + ii) * 1024];
      __builtin_amdgcn_s_setprio(1);
#pragma unroll
      for (int ii = 0; ii < 2; ++ii)
#pragma unroll
        for (int j = 0; j < 4; ++j)
#pragma unroll
          for (int ks = 0; ks < 2; ++ks)
            acc[p * 2 + ii][j] =
                MFMA16(af[ii][ks], bfr[j][ks], acc[p * 2 + ii][j]);
      __builtin_amdgcn_s_setprio(0);
    }
    __builtin_amdgcn_s_barrier();  // all reads of buf done before overwrite
  }
#pragma unroll
  for (int i = 0; i < 8; ++i) {
    const int row = bm + wmh * 128 + i * 16 + lq * 4;
#pragma unroll
    for (int j = 0; j < 4; ++j) {
      const int col = bn + wnq * 64 + j * 16 + lr;
      const float bcol = (EPI >= 1) ? bias[col] : 0.0f;
#pragma unroll
      for (int r = 0; r < 4; ++r) {
        size_t idx = (size_t)(row + r) * Nn + col;
        float vv = acc[i][j][r];
        if (EPI == 2)
          Cb[idx] = (bf16_t)gelu_f(vv + bcol);
        else
          Cb[idx] = (bf16_t)(vv + bcol);
      }
    }
  }
}

// ---------------- W2 GEMM: in-block split-K + fused gelu/resid epilogue ------
__global__ __launch_bounds__(512, 2) void gemm_sk2(const bf16_t* __restrict__ A,
                                                   const bf16_t* __restrict__ W,
                                                   const float* __restrict__ bias,
                                                   const float* __restrict__ resid,
                                                   float* __restrict__ dout) {
  const int K = 4096, Nn = 1024;
  // [group][buf][ A(8192 elems) | B(8192 elems) ] = 128 KB
  __shared__ alignas(16) bf16_t AB[2][2][2 * 8192];
  const int t = threadIdx.x;
  const int tg = t & 255;       // thread id within group
  const int lane = t & 63;
  const int g = t >> 8;         // K-split group (0: lo half, 1: hi half)
  const int w = (t >> 6) & 3;   // wave within group
  const int lin = blockIdx.x + 8 * blockIdx.y;  // 0..255, XCD-friendly
  const int bm = ((lin & 7) * 4 + ((lin >> 6) & 3)) * 128;
  const int bn = ((lin >> 3) & 7) * 128;
  const int kbase = g * 2048;
  const int wm = (w >> 1) * 64;
  const int wn = (w & 1) * 64;
  const int lr = lane & 15;
  const int lq = lane >> 4;
  f32x4 acc[4][4] = {};
  // staging: pre-swizzled global source -> linear LDS (0-conflict pair)
  const bf16_t* apt[4];
  const bf16_t* bpt[4];
  int ldst[4];
#pragma unroll
  for (int c = 0; c < 4; ++c) {
    const int flat = c * 256 + tg;       // 16B chunk 0..1023
    const int r = flat >> 3;             // row 0..127
    const int q = (flat & 7) ^ (r & 7);  // pre-swizzled 8-elem slot
    ldst[c] = flat * 8;
    apt[c] = A + (size_t)(bm + r) * K + kbase + q * 8;
    bpt[c] = W + (size_t)(bn + r) * K + kbase + q * 8;
  }
  // swizzled ds_read base offsets ([128][64] tile, frag adds i*1024)
  int abase[2], bbase[2];
#pragma unroll
  for (int ks = 0; ks < 2; ++ks) {
    const int sw = ((ks * 4 + lq) ^ (lr & 7)) * 8;
    abase[ks] = (wm + lr) * 64 + sw;
    bbase[ks] = (wn + lr) * 64 + sw;
  }
#pragma unroll
  for (int c = 0; c < 4; ++c) {
    async_copy16(apt[c], &AB[g][0][ldst[c]]);
    async_copy16(bpt[c], &AB[g][0][8192 + ldst[c]]);
  }
  for (int kt = 0; kt < 32; ++kt) {
    __syncthreads();  // drains this buffer's loads (in flight one full iter)
    const int k0 = kt << 6;
    const int buf = kt & 1;
    if (kt + 1 < 32) {
#pragma unroll
      for (int c = 0; c < 4; ++c) {
        async_copy16(apt[c] + k0 + 64, &AB[g][buf ^ 1][ldst[c]]);
        async_copy16(bpt[c] + k0 + 64, &AB[g][buf ^ 1][8192 + ldst[c]]);
      }
    }
    const bf16_t* Ab = &AB[g][buf][0];
    const bf16_t* Bb = &AB[g][buf][8192];
    bf16x8 bfr[4][2];
#pragma unroll
    for (int j = 0; j < 4; ++j)
#pragma unroll
      for (int ks = 0; ks < 2; ++ks)
        bfr[j][ks] = *(const bf16x8*)&Bb[bbase[ks] + j * 1024];
#pragma unroll
    for (int i = 0; i < 4; ++i) {
      bf16x8 af0 = *(const bf16x8*)&Ab[abase[0] + i * 1024];
      bf16x8 af1 = *(const bf16x8*)&Ab[abase[1] + i * 1024];
#pragma unroll
      for (int j = 0; j < 4; ++j) {
        acc[i][j] = MFMA16(af0, bfr[j][0], acc[i][j]);
        acc[i][j] = MFMA16(af1, bfr[j][1], acc[i][j]);
      }
    }
  }
  // ---- in-block split-K reduction + fused epilogue ----
  __syncthreads();  // all LDS reads of the K-loop complete
  float* red = (float*)&AB[0][0][0];  // 64 KB of the 128 KB LDS
  if (g == 1) {
#pragma unroll
    for (int i = 0; i < 4; ++i)
#pragma unroll
      for (int j = 0; j < 4; ++j)
#pragma unroll
        for (int r = 0; r < 4; ++r)
          red[(wm + i * 16 + lq * 4 + r) * 128 + wn + j * 16 + lr] =
              acc[i][j][r];
  }
  __syncthreads();
  if (g == 0) {
#pragma unroll
    for (int i = 0; i < 4; ++i) {
      const int row = bm + wm + i * 16 + lq * 4;
#pragma unroll
      for (int j = 0; j < 4; ++j) {
        const int col = bn + wn + j * 16 + lr;
        const float bcol = bias[col];
#pragma unroll
        for (int r = 0; r < 4; ++r) {
          const size_t idx = (size_t)(row + r) * Nn + col;
          const float v = acc[i][j][r] +
                          red[(wm + i * 16 + lq * 4 + r) * 128 + wn + j * 16 + lr];
          dout[idx] = gelu_f(v + bcol) + resid[idx];
        }
      }
    }
  }
}

// ---------------- 64x128xBK64 GEMM, dbuf + XCD-locality swizzle --------------
template <int EPI>
__global__ __launch_bounds__(256, 4) void gemm64_bt(const bf16_t* __restrict__ A,
                                                    const bf16_t* __restrict__ W,
                                                    float* __restrict__ Cf,
                                                    const float* __restrict__ bias,
                                                    const float* __restrict__ resid,
                                                    int M, int Nn, int K) {
  __shared__ alignas(16) bf16_t As[2][2 * 64 * 32];
  __shared__ alignas(16) bf16_t Bs[2][2 * 128 * 32];
  const int t = threadIdx.x;
  const int lane = t & 63;
  const int w = t >> 6;
  const int lin = blockIdx.x + 8 * blockIdx.y;
  const int bm = ((lin & 7) * 8 + (lin >> 6)) * 64;
  const int bn = ((lin >> 3) & 7) * 128;
  const int wm = (w >> 1) * 32;
  const int wn = (w & 1) * 64;
  const int lr = lane & 15;
  const int lq = lane >> 4;
  f32x4 acc[2][4] = {};
  const bf16_t* Ap[2];
  const bf16_t* Bp[4];
#pragma unroll
  for (int c = 0; c < 2; ++c) {
    const int flat = c * 256 + t;
    const int p = flat >> 8;
    const int r = (flat >> 2) & 63;
    const int q = flat & 3;
    Ap[c] = A + (size_t)(bm + r) * K + p * 32 + q * 8;
  }
#pragma unroll
  for (int c = 0; c < 4; ++c) {
    const int flat = c * 256 + t;
    const int p = flat >> 9;
    const int r = (flat >> 2) & 127;
    const int q = flat & 3;
    Bp[c] = W + (size_t)(bn + r) * K + p * 32 + q * 8;
  }
#pragma unroll
  for (int c = 0; c < 2; ++c) async_copy16(Ap[c], &As[0][(c * 256 + t) * 8]);
#pragma unroll
  for (int c = 0; c < 4; ++c) async_copy16(Bp[c], &Bs[0][(c * 256 + t) * 8]);
  int buf = 0;
  for (int k0 = 0; k0 < K; k0 += 64) {
    __syncthreads();
    const int nb = buf ^ 1;
    if (k0 + 64 < K) {
#pragma unroll
      for (int c = 0; c < 2; ++c)
        async_copy16(Ap[c] + k0 + 64, &As[nb][(c * 256 + t) * 8]);
#pragma unroll
      for (int c = 0; c < 4; ++c)
        async_copy16(Bp[c] + k0 + 64, &Bs[nb][(c * 256 + t) * 8]);
    }
#pragma unroll
    for (int half = 0; half < 2; ++half) {
      const bf16_t* Ash = &As[buf][half * 2048];
      const bf16_t* Bsh = &Bs[buf][half * 4096];
      bf16x8 af[2], bfr[4];
#pragma unroll
      for (int i = 0; i < 2; ++i)
        af[i] = *(const bf16x8*)&Ash[(wm + i * 16 + lr) * 32 + lq * 8];
#pragma unroll
      for (int j = 0; j < 4; ++j)
        bfr[j] = *(const bf16x8*)&Bsh[(wn + j * 16 + lr) * 32 + lq * 8];
#pragma unroll
      for (int i = 0; i < 2; ++i)
#pragma unroll
        for (int j = 0; j < 4; ++j)
          acc[i][j] = MFMA16(af[i], bfr[j], acc[i][j]);
    }
    buf = nb;
  }
#pragma unroll
  for (int i = 0; i < 2; ++i) {
    const int row = bm + wm + i * 16 + lq * 4;
#pragma unroll
    for (int j = 0; j < 4; ++j) {
      const int col = bn + wn + j * 16 + lr;
      float bcol = bias[col];
#pragma unroll
      for (int r = 0; r < 4; ++r) {
        size_t idx = (size_t)(row + r) * Nn + col;
        float vv = acc[i][j][r];
        if (EPI == 1)
          Cf[idx] = vv + bcol + resid[idx];
        else
          Cf[idx] = gelu_f(vv + bcol) + resid[idx];
      }
    }
  }
}

// ---------------- fused QKV GEMM (BK32 dbuf); Q pre-scaled, V transposed -----
__global__ __launch_bounds__(256, 4) void gemm_qkv(const bf16_t* __restrict__ A,
                                                   const bf16_t* __restrict__ W0,
                                                   const bf16_t* __restrict__ W1,
                                                   const bf16_t* __restrict__ W2,
                                                   bf16_t* __restrict__ C0,
                                                   bf16_t* __restrict__ C1,
                                                   bf16_t* __restrict__ vt) {
  const int z = blockIdx.z;
  const bf16_t* W = (z == 0) ? W0 : ((z == 1) ? W1 : W2);
  const float osc = (z == 0) ? 0.045084220027780106f : 1.0f;
  const int K = 1024, Nn = 1024;
  __shared__ alignas(16) bf16_t As[2][128 * 32];
  __shared__ alignas(16) bf16_t Bs[2][128 * 32];
  const int t = threadIdx.x;
  const int lane = t & 63;
  const int w = t >> 6;
  const int bm = blockIdx.y * 128;
  const int bn = blockIdx.x * 128;
  const int wm = (w >> 1) * 64;
  const int wn = (w & 1) * 64;
  const int lr = lane & 15;
  const int lq = lane >> 4;
  f32x4 acc[4][4] = {};
  const bf16_t* Ap[2];
  const bf16_t* Bp[2];
#pragma unroll
  for (int c = 0; c < 2; ++c) {
    const int flat = c * 256 + t;
    const int r = flat >> 2;
    const int q = flat & 3;
    Ap[c] = A + (size_t)(bm + r) * K + q * 8;
    Bp[c] = W + (size_t)(bn + r) * K + q * 8;
  }
#pragma unroll
  for (int c = 0; c < 2; ++c) {
    async_copy16(Ap[c], &As[0][(c * 256 + t) * 8]);
    async_copy16(Bp[c], &Bs[0][(c * 256 + t) * 8]);
  }
  int buf = 0;
  for (int k0 = 0; k0 < K; k0 += 32) {
    __syncthreads();
    const int nb = buf ^ 1;
    if (k0 + 32 < K) {
#pragma unroll
      for (int c = 0; c < 2; ++c) {
        async_copy16(Ap[c] + k0 + 32, &As[nb][(c * 256 + t) * 8]);
        async_copy16(Bp[c] + k0 + 32, &Bs[nb][(c * 256 + t) * 8]);
      }
    }
    bf16x8 af[4], bfr[4];
#pragma unroll
    for (int i = 0; i < 4; ++i)
      af[i] = *(const bf16x8*)&As[buf][(wm + i * 16 + lr) * 32 + lq * 8];
#pragma unroll
    for (int j = 0; j < 4; ++j)
      bfr[j] = *(const bf16x8*)&Bs[buf][(wn + j * 16 + lr) * 32 + lq * 8];
#pragma unroll
    for (int i = 0; i < 4; ++i)
#pragma unroll
      for (int j = 0; j < 4; ++j)
        acc[i][j] = MFMA16(af[i], bfr[j], acc[i][j]);
    buf = nb;
  }
  if (z == 2) {
    // V transposed: vt[((b*16 + col/64)*64 + col%64)*2048 + n], quad = 4 n's
#pragma unroll
    for (int i = 0; i < 4; ++i) {
      const int row0 = bm + wm + i * 16 + lq * 4;  // n index base
      const int b = row0 >> 11;
      const int n = row0 & 2047;
#pragma unroll
      for (int j = 0; j < 4; ++j) {
        const int col = bn + wn + j * 16 + lr;  // global d (h*64 + dloc)
        bf16x4 pv;
#pragma unroll
        for (int r = 0; r < 4; ++r) pv[r] = (bf16_t)acc[i][j][r];
        *(bf16x4*)&vt[((size_t)(b * 16 + (col >> 6)) * 64 + (col & 63)) * 2048 + n] = pv;
      }
    }
  } else {
    bf16_t* Cb = (z == 0) ? C0 : C1;
#pragma unroll
    for (int i = 0; i < 4; ++i) {
      const int row = bm + wm + i * 16 + lq * 4;
#pragma unroll
      for (int j = 0; j < 4; ++j) {
        const int col = bn + wn + j * 16 + lr;
#pragma unroll
        for (int r = 0; r < 4; ++r)
          Cb[(size_t)(row + r) * Nn + col] = (bf16_t)(acc[i][j][r] * osc);
      }
    }
  }
}

// ---------------- flash attention v12: triple-buffer + counted vmcnt ---------
// Grid (16 q-tiles, 32 bh), 2 blocks/CU. At this occupancy the old
// __syncthreads-per-iter loop drained vmcnt to 0 every iteration (latency
// visible: Mfma 26% / VALU 40% / HBM 19%, nothing saturated). Now: 3 K/V
// buffers; stage tile i+2 each iter; vmcnt(8) keeps tiles i+1,i+2 in flight
// across the barrier (never drains in-loop); two raw s_barriers per iter
// (same proven pattern as gemm256). setprio(1) around MFMA clusters (T5,
// +4-7% on attn, m191).
__global__ __launch_bounds__(256, 4) void flash_attn(const bf16_t* __restrict__ q,
                                                     const bf16_t* __restrict__ k,
                                                     const bf16_t* __restrict__ vt,
                                                     bf16_t* __restrict__ attn) {
  __shared__ alignas(16) bf16_t Ks[3][64 * 64];
  __shared__ alignas(16) bf16_t Vs[3][64 * 64];
  const int t = threadIdx.x;
  const int lane = t & 63;
  const int w = t >> 6;
  const int lr = lane & 15;
  const int lq = lane >> 4;
  const int qt = blockIdx.x;   // query tile 0..15 (128 wide)
  const int bh = blockIdx.y;   // b*16+h
  const int b = bh >> 4;
  const int h = bh & 15;
  const size_t rowbase = (size_t)b * 2048;
  const int hcol = h * 64;
  const bf16_t* vtp = vt + (size_t)bh * 64 * 2048;

  bf16x8 qf[2][2];
#pragma unroll
  for (int u = 0; u < 2; ++u) {
    size_t qrow = rowbase + qt * 128 + w * 32 + u * 16 + lr;
    const bf16_t* qp = q + qrow * 1024 + hcol + lq * 8;
    qf[u][0] = *(const bf16x8*)qp;
    qf[u][1] = *(const bf16x8*)(qp + 32);
  }
  f32x4 of[2][4] = {};
  float lsum[2] = {0.0f, 0.0f};

  const int sr0 = t >> 3;
  const int sc0 = (t & 7) ^ (sr0 & 7);
  const int sr1 = (256 + t) >> 3;
  const int sc1 = (t & 7) ^ (sr1 & 7);

  auto stage = [&](int tile, int bi) {
    const size_t krow0 = rowbase + (size_t)tile * 64;
    async_copy16(k + (krow0 + sr0) * 1024 + hcol + sc0 * 8, &Ks[bi][t * 8]);
    async_copy16(vtp + (size_t)sr0 * 2048 + tile * 64 + sc0 * 8, &Vs[bi][t * 8]);
    async_copy16(k + (krow0 + sr1) * 1024 + hcol + sc1 * 8, &Ks[bi][2048 + t * 8]);
    async_copy16(vtp + (size_t)sr1 * 2048 + tile * 64 + sc1 * 8, &Vs[bi][2048 + t * 8]);
  };
  stage(0, 0);
  stage(1, 1);
  int buf = 0;   // buffer holding tile i
  int sbuf = 2;  // buffer to stage tile i+2 into
  for (int i = 0; i < 32; ++i) {
    if (i + 2 < 32) {
      stage(i + 2, sbuf);
      // tiles i+1, i+2 (8 loads/thread) stay in flight; tile i retired
      asm volatile("s_waitcnt vmcnt(8)" ::: "memory");
    } else if (i + 1 < 32) {
      asm volatile("s_waitcnt vmcnt(4)" ::: "memory");
    } else {
      asm volatile("s_waitcnt vmcnt(0)" ::: "memory");
    }
    __builtin_amdgcn_s_barrier();  // tile i published to all waves
    // ---- QK^T: sc[u][s][r] = S[k=16s+4*lq+r][q = w*32+u*16+lr] ----
    f32x4 sc[2][4];
    __builtin_amdgcn_s_setprio(1);
#pragma unroll
    for (int s = 0; s < 4; ++s) {
      const int r2 = s * 16 + lr;
      bf16x8 kf0 = *(const bf16x8*)&Ks[buf][r2 * 64 + ((lq) ^ (r2 & 7)) * 8];
      bf16x8 kf1 = *(const bf16x8*)&Ks[buf][r2 * 64 + ((4 + lq) ^ (r2 & 7)) * 8];
#pragma unroll
      for (int u = 0; u < 2; ++u) {
        f32x4 c = {};
        c = MFMA16(kf0, qf[u][0], c);
        c = MFMA16(kf1, qf[u][1], c);
        sc[u][s] = c;
      }
    }
    __builtin_amdgcn_s_setprio(0);
    // ---- exp, row-sum, in-register transpose into B-fragments ----
    bf16x8 pf[2][2];
#pragma unroll
    for (int u = 0; u < 2; ++u) {
      float e[4][4];
#pragma unroll
      for (int s = 0; s < 4; ++s)
#pragma unroll
        for (int r = 0; r < 4; ++r) {
          e[s][r] = EXP2F(sc[u][s][r]);
          lsum[u] += e[s][r];
        }
      unsigned w0[4], w1[4];
#pragma unroll
      for (int s = 0; s < 4; ++s) {
        w0[s] = cvt_pk_bf16(e[s][0], e[s][1]);
        w1[s] = cvt_pk_bf16(e[s][2], e[s][3]);
      }
#pragma unroll
      for (int half = 0; half < 2; ++half) {
        unsigned a0 = w0[2 * half], a1 = w0[2 * half + 1];
        unsigned b0 = w1[2 * half], b1 = w1[2 * half + 1];
        plane32_swap(a0, a1);
        plane16_swap(a0, a1);
        plane32_swap(b0, b1);
        plane16_swap(b0, b1);
        union {
          bf16x8 v;
          unsigned wd[4];
        } pu;
        pu.wd[0] = a0;
        pu.wd[1] = b0;
        pu.wd[2] = a1;
        pu.wd[3] = b1;
        pf[u][half] = pu.v;
      }
    }
    // ---- PV: O^T[d][q] += V^T (A) x P (B) ----
    __builtin_amdgcn_s_setprio(1);
#pragma unroll
    for (int d = 0; d < 4; ++d) {
      const int rv = d * 16 + lr;
      bf16x8 vf0 = *(const bf16x8*)&Vs[buf][rv * 64 + ((lq) ^ (rv & 7)) * 8];
      bf16x8 vf1 = *(const bf16x8*)&Vs[buf][rv * 64 + ((4 + lq) ^ (rv & 7)) * 8];
#pragma unroll
      for (int u = 0; u < 2; ++u) {
        of[u][d] = MFMA16(vf0, pf[u][0], of[u][d]);
        of[u][d] = MFMA16(vf1, pf[u][1], of[u][d]);
      }
    }
    __builtin_amdgcn_s_setprio(0);
    // my LDS reads of buf are complete before anyone overwrites it (stage of
    // tile i+3, issued after the next barrier crossing)
    asm volatile("s_waitcnt lgkmcnt(0)" ::: "memory");
    __builtin_amdgcn_s_barrier();
    buf = (buf == 2) ? 0 : buf + 1;
    sbuf = (sbuf == 2) ? 0 : sbuf + 1;
  }
  // of[u][d][r] = O^T[dglob = d*16 + lq*4 + r][q = qt*128 + w*32 + u*16 + lr]
  // normalize by the full row-sum (reduced across lq groups) and store attn
#pragma unroll
  for (int u = 0; u < 2; ++u) {
    float l = lsum[u];
    l += __shfl_xor(l, 16);
    l += __shfl_xor(l, 32);
    const float inv = 1.0f / l;
    const size_t qrow = rowbase + qt * 128 + w * 32 + u * 16 + lr;
#pragma unroll
    for (int d = 0; d < 4; ++d) {
      bf16x4 pv;
#pragma unroll
      for (int r = 0; r < 4; ++r) pv[r] = (bf16_t)(of[u][d][r] * inv);
      *(bf16x4*)&attn[qrow * 1024 + hcol + d * 16 + lq * 4] = pv;
    }
  }
}

extern "C" void kernel_launch(void* const* d_in, const int* in_sizes, int n_in,
                              void* d_out, int out_size, void* d_ws, size_t ws_size,
                              hipStream_t stream) {
  (void)in_sizes;
  (void)n_in;
  (void)out_size;
  (void)ws_size;
  const float* x = (const float*)d_in[0];
  const float* la1g = (const float*)d_in[1];
  const float* la1b = (const float*)d_in[2];
  const float* Wq = (const float*)d_in[3];
  const float* Wk = (const float*)d_in[4];
  const float* Wv = (const float*)d_in[5];
  const float* Wo = (const float*)d_in[6];
  const float* bo = (const float*)d_in[7];
  const float* la2g = (const float*)d_in[8];
  const float* la2b = (const float*)d_in[9];
  const float* W1 = (const float*)d_in[10];
  const float* b1 = (const float*)d_in[11];
  const float* W2 = (const float*)d_in[12];
  const float* b2 = (const float*)d_in[13];
  char* ws = (char*)d_ws;
  const size_t MB = (size_t)1 << 20;
  bf16_t* wq_b = (bf16_t*)(ws + 0 * MB);
  bf16_t* wk_b = (bf16_t*)(ws + 2 * MB);
  bf16_t* wv_b = (bf16_t*)(ws + 4 * MB);
  bf16_t* wo_b = (bf16_t*)(ws + 6 * MB);
  bf16_t* w1_b = (bf16_t*)(ws + 8 * MB);
  bf16_t* w2_b = (bf16_t*)(ws + 16 * MB);
  bf16_t* hbuf = (bf16_t*)(ws + 24 * MB);  // ln1 out, QKV input
  bf16_t* qb = (bf16_t*)(ws + 32 * MB);
  bf16_t* kb = (bf16_t*)(ws + 40 * MB);
  bf16_t* vt = (bf16_t*)(ws + 48 * MB);    // V written transposed by QKV
  bf16_t* attn = (bf16_t*)(ws + 56 * MB);
  float* outb = (float*)(ws + 64 * MB);    // 16 MB fp32
  bf16_t* h2 = (bf16_t*)(ws + 80 * MB);    // 8 MB
  bf16_t* m1 = (bf16_t*)(ws + 88 * MB);    // 32 MB (88-120)
  float* dout = (float*)d_out;

  cvt_all<<<dim3(1024, 12), 256, 0, stream>>>(Wq, Wk, Wv, Wo, W1, W2, wq_b,
                                              wk_b, wv_b, wo_b, w1_b, w2_b);
  ln_k<<<4096, 256, 0, stream>>>(x, la1g, la1b, hbuf);
  gemm_qkv<<<dim3(8, 32, 3), 256, 0, stream>>>(hbuf, wq_b, wk_b, wv_b, qb, kb, vt);
  flash_attn<<<dim3(16, 32), 256, 0, stream>>>(qb, kb, vt, attn);
  gemm64_bt<1><<<dim3(8, 64), 256, 0, stream>>>(attn, wo_b, outb, bo, x, 4096, 1024, 1024);
  ln_k<<<4096, 256, 0, stream>>>(outb, la2g, la2b, h2);
  gemm256<2><<<256, 512, 0, stream>>>(h2, w1_b, m1, b1, 4096, 1024);
  gemm_sk2<<<dim3(8, 32), 512, 0, stream>>>(m1, w2_b, b2, outb, dout);
}

// Round 9
// 318.184 us; speedup vs baseline: 1.0174x; 1.0174x over previous
//
#include <hip/hip_runtime.h>
#include <hip/hip_bf16.h>

typedef __bf16 bf16_t;
typedef __bf16 bf16x4 __attribute__((ext_vector_type(4)));
typedef __bf16 bf16x8 __attribute__((ext_vector_type(8)));
typedef float f32x4 __attribute__((ext_vector_type(4)));
typedef unsigned uintx2 __attribute__((ext_vector_type(2)));

#define MFMA16(a, b, c) __builtin_amdgcn_mfma_f32_16x16x32_bf16((a), (b), (c), 0, 0, 0)

#if defined(__has_builtin) && __has_builtin(__builtin_amdgcn_exp2f)
#define EXP2F(x) __builtin_amdgcn_exp2f(x)
#else
#define EXP2F(x) exp2f(x)
#endif

__device__ __forceinline__ void async_copy16(const void* g, void* l) {
#if defined(__has_builtin) && __has_builtin(__builtin_amdgcn_global_load_lds)
  __builtin_amdgcn_global_load_lds((__attribute__((address_space(1))) void*)g,
                                   (__attribute__((address_space(3))) void*)l, 16, 0, 0);
#else
  *(bf16x8*)l = *(const bf16x8*)g;
#endif
}

// tanh-approx GELU in sigmoid form: x*sigmoid(2c(x+0.044715x^3)); |err|<~3e-3
__device__ __forceinline__ float gelu_f(float x) {
  float u = x * (1.5957691216057308f + 0.07135481283f * x * x);
  return x / (1.0f + __expf(-u));
}

// pack two f32 -> one u32 of 2 bf16 (low = lo)
__device__ __forceinline__ unsigned cvt_pk_bf16(float lo, float hi) {
  unsigned r;
  asm("v_cvt_pk_bf16_f32 %0, %1, %2" : "=v"(r) : "v"(lo), "v"(hi));
  return r;
}

// pair swap: a' = {a[0:31], b[0:31]}, b' = {a[32:63], b[32:63]}
__device__ __forceinline__ void plane32_swap(unsigned& a, unsigned& b) {
#if defined(__has_builtin) && __has_builtin(__builtin_amdgcn_permlane32_swap)
  uintx2 r = __builtin_amdgcn_permlane32_swap(a, b, false, false);
  a = r[0];
  b = r[1];
#else
  const int lane = threadIdx.x & 63;
  unsigned as = (unsigned)__shfl_xor((int)a, 32);
  unsigned bs = (unsigned)__shfl_xor((int)b, 32);
  unsigned na = (lane < 32) ? a : bs;
  unsigned nb = (lane < 32) ? as : b;
  a = na;
  b = nb;
#endif
}

// per-16 swap within each half: a' = {a@0,b@0,a@2,b@2}, b' = {a@1,b@1,a@3,b@3}
__device__ __forceinline__ void plane16_swap(unsigned& a, unsigned& b) {
#if defined(__has_builtin) && __has_builtin(__builtin_amdgcn_permlane16_swap)
  uintx2 r = __builtin_amdgcn_permlane16_swap(a, b, false, false);
  a = r[0];
  b = r[1];
#else
  const int lane = threadIdx.x & 63;
  unsigned as = (unsigned)__shfl_xor((int)a, 16);
  unsigned bs = (unsigned)__shfl_xor((int)b, 16);
  unsigned na = (lane & 16) ? bs : a;
  unsigned nb = (lane & 16) ? b : as;
  a = na;
  b = nb;
#endif
}

// ---------------- all weight fp32 -> bf16 converts, ONE dispatch -------------
__global__ __launch_bounds__(256) void cvt_all(const float* __restrict__ sq,
                                               const float* __restrict__ sk,
                                               const float* __restrict__ sv,
                                               const float* __restrict__ so,
                                               const float* __restrict__ s1,
                                               const float* __restrict__ s2,
                                               bf16_t* __restrict__ dq,
                                               bf16_t* __restrict__ dk,
                                               bf16_t* __restrict__ dv,
                                               bf16_t* __restrict__ do_,
                                               bf16_t* __restrict__ d1,
                                               bf16_t* __restrict__ d2) {
  const int y = blockIdx.y;
  const float* s;
  bf16_t* d;
  if (y < 4) {
    s = (y == 0) ? sq : (y == 1) ? sk : (y == 2) ? sv : so;
    d = (y == 0) ? dq : (y == 1) ? dk : (y == 2) ? dv : do_;
  } else if (y < 8) {
    s = s1 + (size_t)(y - 4) * 1048576;
    d = d1 + (size_t)(y - 4) * 1048576;
  } else {
    s = s2 + (size_t)(y - 8) * 1048576;
    d = d2 + (size_t)(y - 8) * 1048576;
  }
  int i = (blockIdx.x * 256 + threadIdx.x) * 4;
  float4 f = *(const float4*)(s + i);
  d[i + 0] = (bf16_t)f.x;
  d[i + 1] = (bf16_t)f.y;
  d[i + 2] = (bf16_t)f.z;
  d[i + 3] = (bf16_t)f.w;
}

// ---------------- layernorm over 1024 cols, one block per row ----------------
__global__ __launch_bounds__(256) void ln_k(const float* __restrict__ x,
                                            const float* __restrict__ g,
                                            const float* __restrict__ b,
                                            bf16_t* __restrict__ o) {
  __shared__ float red[8];
  const int t = threadIdx.x;
  const size_t row = blockIdx.x;
  float4 xv = ((const float4*)(x + row * 1024))[t];
  float s = xv.x + xv.y + xv.z + xv.w;
  float s2 = xv.x * xv.x + xv.y * xv.y + xv.z * xv.z + xv.w * xv.w;
#pragma unroll
  for (int off = 1; off < 64; off <<= 1) {
    s += __shfl_xor(s, off);
    s2 += __shfl_xor(s2, off);
  }
  if ((t & 63) == 0) {
    red[t >> 6] = s;
    red[4 + (t >> 6)] = s2;
  }
  __syncthreads();
  s = red[0] + red[1] + red[2] + red[3];
  s2 = red[4] + red[5] + red[6] + red[7];
  const float mu = s * (1.0f / 1024.0f);
  const float rstd = rsqrtf(s2 * (1.0f / 1024.0f) - mu * mu + 1e-5f);
  float4 gv = ((const float4*)g)[t];
  float4 bv = ((const float4*)b)[t];
  bf16_t* op = o + row * 1024 + t * 4;
  op[0] = (bf16_t)((xv.x - mu) * rstd * gv.x + bv.x);
  op[1] = (bf16_t)((xv.y - mu) * rstd * gv.y + bv.y);
  op[2] = (bf16_t)((xv.z - mu) * rstd * gv.z + bv.z);
  op[3] = (bf16_t)((xv.w - mu) * rstd * gv.w + bv.w);
}

// ---------------- 256x256xBK64 GEMM, slab waves + B-register cache -----------
template <int EPI>
__global__ __launch_bounds__(512, 2) void gemm256(const bf16_t* __restrict__ A,
                                                  const bf16_t* __restrict__ W,
                                                  bf16_t* __restrict__ Cb,
                                                  const float* __restrict__ bias,
                                                  int Nn, int K) {
  __shared__ alignas(16) bf16_t As[2][2 * 128 * 64];
  __shared__ alignas(16) bf16_t Bs[2][2 * 128 * 64];
  const int t = threadIdx.x;
  const int lane = t & 63;
  const int w = t >> 6;
  // bijective XCD swizzle (gridDim.x % 8 == 0)
  const int cpx = gridDim.x >> 3;
  const int bid = blockIdx.x;
  const int swz = (bid & 7) * cpx + (bid >> 3);
  const int nbx = Nn >> 8;
  const int bm = (swz / nbx) * 256;
  const int bn = (swz % nbx) * 256;
  const int wmh = w >> 2;  // A half-tile this wave consumes (rows wmh*128..)
  const int wnq = w & 3;   // 64-col slice
  const int lr = lane & 15;
  const int lq = lane >> 4;
  f32x4 acc[8][4] = {};
  // swizzled ds_read base offsets; frag (i or j) adds i*1024 (16 rows * 64)
  int abase[2], bbase[2];
#pragma unroll
  for (int ks = 0; ks < 2; ++ks) {
    const int sw = ((ks * 4 + lq) ^ (lr & 7)) * 8;
    abase[ks] = wmh * 8192 + lr * 64 + sw;
    bbase[ks] = (wnq >> 1) * 8192 + (wnq & 1) * 4096 + lr * 64 + sw;
  }
  // per-thread staging pointers (pre-swizzled global source), linear LDS dst
  const bf16_t* apt[2][2];
  const bf16_t* bpt[2][2];
  int ldst[2];
#pragma unroll
  for (int c = 0; c < 2; ++c) {
    const int flat = c * 512 + t;        // 16B chunk 0..1023 within a half
    const int r = flat >> 3;             // row within half 0..127
    const int q = (flat & 7) ^ (r & 7);  // pre-swizzled 8-elem slot
    ldst[c] = flat * 8;
#pragma unroll
    for (int h = 0; h < 2; ++h) {
      apt[h][c] = A + (size_t)(bm + h * 128 + r) * K + q * 8;
      bpt[h][c] = W + (size_t)(bn + h * 128 + r) * K + q * 8;
    }
  }
  const int NT = K >> 6;
  // prologue: issue tile 0 stages
#pragma unroll
  for (int c = 0; c < 2; ++c) async_copy16(apt[0][c], &As[0][ldst[c]]);
#pragma unroll
  for (int c = 0; c < 2; ++c) async_copy16(bpt[0][c], &Bs[0][ldst[c]]);
#pragma unroll
  for (int c = 0; c < 2; ++c) async_copy16(bpt[1][c], &Bs[0][8192 + ldst[c]]);
#pragma unroll
  for (int c = 0; c < 2; ++c) async_copy16(apt[1][c], &As[0][8192 + ldst[c]]);
  for (int kt = 0; kt < NT; ++kt) {
    const bf16_t* Ab = As[kt & 1];
    const bf16_t* Bb = Bs[kt & 1];
    bf16_t* Asn = As[(kt & 1) ^ 1];
    bf16_t* Bsn = Bs[(kt & 1) ^ 1];
    const int nk = (kt + 1) << 6;
    if (kt + 1 < NT) {
#pragma unroll
      for (int c = 0; c < 2; ++c) async_copy16(apt[0][c] + nk, Asn + ldst[c]);
#pragma unroll
      for (int c = 0; c < 2; ++c) async_copy16(bpt[0][c] + nk, Bsn + ldst[c]);
#pragma unroll
      for (int c = 0; c < 2; ++c)
        async_copy16(bpt[1][c] + nk, Bsn + 8192 + ldst[c]);
#pragma unroll
      for (int c = 0; c < 2; ++c)
        async_copy16(apt[1][c] + nk, Asn + 8192 + ldst[c]);
      // 8 newest (this tile's stages) may stay in flight; all older retired
      asm volatile("s_waitcnt vmcnt(8)" ::: "memory");
    } else {
      asm volatile("s_waitcnt vmcnt(0)" ::: "memory");
    }
    __builtin_amdgcn_s_barrier();  // buf published to all waves
    // B fragments once per K-tile (held in regs across all 4 phases)
    bf16x8 bfr[4][2];
#pragma unroll
    for (int j = 0; j < 4; ++j)
#pragma unroll
      for (int ks = 0; ks < 2; ++ks)
        bfr[j][ks] = *(const bf16x8*)&Bb[bbase[ks] + j * 1024];
    // 4 phases over the wave's 8 m-frags
#pragma unroll
    for (int p = 0; p < 4; ++p) {
      bf16x8 af[2][2];
#pragma unroll
      for (int ii = 0; ii < 2; ++ii)
#pragma unroll
        for (int ks = 0; ks < 2; ++ks)
          af[ii][ks] = *(const bf16x8*)&Ab[abase[ks] + (p * 2 + ii) * 1024];
      __builtin_amdgcn_s_setprio(1);
#pragma unroll
      for (int ii = 0; ii < 2; ++ii)
#pragma unroll
        for (int j = 0; j < 4; ++j)
#pragma unroll
          for (int ks = 0; ks < 2; ++ks)
            acc[p * 2 + ii][j] =
                MFMA16(af[ii][ks], bfr[j][ks], acc[p * 2 + ii][j]);
      __builtin_amdgcn_s_setprio(0);
    }
    __builtin_amdgcn_s_barrier();  // all reads of buf done before overwrite
  }
#pragma unroll
  for (int i = 0; i < 8; ++i) {
    const int row = bm + wmh * 128 + i * 16 + lq * 4;
#pragma unroll
    for (int j = 0; j < 4; ++j) {
      const int col = bn + wnq * 64 + j * 16 + lr;
      const float bcol = (EPI >= 1) ? bias[col] : 0.0f;
#pragma unroll
      for (int r = 0; r < 4; ++r) {
        size_t idx = (size_t)(row + r) * Nn + col;
        float vv = acc[i][j][r];
        if (EPI == 2)
          Cb[idx] = (bf16_t)gelu_f(vv + bcol);
        else
          Cb[idx] = (bf16_t)(vv + bcol);
      }
    }
  }
}

// ---------------- W2 GEMM: in-block split-K + fused gelu/resid epilogue ------
__global__ __launch_bounds__(512, 2) void gemm_sk2(const bf16_t* __restrict__ A,
                                                   const bf16_t* __restrict__ W,
                                                   const float* __restrict__ bias,
                                                   const float* __restrict__ resid,
                                                   float* __restrict__ dout) {
  const int K = 4096, Nn = 1024;
  // [group][buf][ A(8192 elems) | B(8192 elems) ] = 128 KB
  __shared__ alignas(16) bf16_t AB[2][2][2 * 8192];
  const int t = threadIdx.x;
  const int tg = t & 255;       // thread id within group
  const int lane = t & 63;
  const int g = t >> 8;         // K-split group (0: lo half, 1: hi half)
  const int w = (t >> 6) & 3;   // wave within group
  const int lin = blockIdx.x + 8 * blockIdx.y;  // 0..255, XCD-friendly
  const int bm = ((lin & 7) * 4 + ((lin >> 6) & 3)) * 128;
  const int bn = ((lin >> 3) & 7) * 128;
  const int kbase = g * 2048;
  const int wm = (w >> 1) * 64;
  const int wn = (w & 1) * 64;
  const int lr = lane & 15;
  const int lq = lane >> 4;
  f32x4 acc[4][4] = {};
  // staging: pre-swizzled global source -> linear LDS (0-conflict pair)
  const bf16_t* apt[4];
  const bf16_t* bpt[4];
  int ldst[4];
#pragma unroll
  for (int c = 0; c < 4; ++c) {
    const int flat = c * 256 + tg;       // 16B chunk 0..1023
    const int r = flat >> 3;             // row 0..127
    const int q = (flat & 7) ^ (r & 7);  // pre-swizzled 8-elem slot
    ldst[c] = flat * 8;
    apt[c] = A + (size_t)(bm + r) * K + kbase + q * 8;
    bpt[c] = W + (size_t)(bn + r) * K + kbase + q * 8;
  }
  // swizzled ds_read base offsets ([128][64] tile, frag adds i*1024)
  int abase[2], bbase[2];
#pragma unroll
  for (int ks = 0; ks < 2; ++ks) {
    const int sw = ((ks * 4 + lq) ^ (lr & 7)) * 8;
    abase[ks] = (wm + lr) * 64 + sw;
    bbase[ks] = (wn + lr) * 64 + sw;
  }
#pragma unroll
  for (int c = 0; c < 4; ++c) {
    async_copy16(apt[c], &AB[g][0][ldst[c]]);
    async_copy16(bpt[c], &AB[g][0][8192 + ldst[c]]);
  }
  for (int kt = 0; kt < 32; ++kt) {
    __syncthreads();  // drains this buffer's loads (in flight one full iter)
    const int k0 = kt << 6;
    const int buf = kt & 1;
    if (kt + 1 < 32) {
#pragma unroll
      for (int c = 0; c < 4; ++c) {
        async_copy16(apt[c] + k0 + 64, &AB[g][buf ^ 1][ldst[c]]);
        async_copy16(bpt[c] + k0 + 64, &AB[g][buf ^ 1][8192 + ldst[c]]);
      }
    }
    const bf16_t* Ab = &AB[g][buf][0];
    const bf16_t* Bb = &AB[g][buf][8192];
    bf16x8 bfr[4][2];
#pragma unroll
    for (int j = 0; j < 4; ++j)
#pragma unroll
      for (int ks = 0; ks < 2; ++ks)
        bfr[j][ks] = *(const bf16x8*)&Bb[bbase[ks] + j * 1024];
#pragma unroll
    for (int i = 0; i < 4; ++i) {
      bf16x8 af0 = *(const bf16x8*)&Ab[abase[0] + i * 1024];
      bf16x8 af1 = *(const bf16x8*)&Ab[abase[1] + i * 1024];
#pragma unroll
      for (int j = 0; j < 4; ++j) {
        acc[i][j] = MFMA16(af0, bfr[j][0], acc[i][j]);
        acc[i][j] = MFMA16(af1, bfr[j][1], acc[i][j]);
      }
    }
  }
  // ---- in-block split-K reduction + fused epilogue ----
  __syncthreads();  // all LDS reads of the K-loop complete
  float* red = (float*)&AB[0][0][0];  // 64 KB of the 128 KB LDS
  if (g == 1) {
#pragma unroll
    for (int i = 0; i < 4; ++i)
#pragma unroll
      for (int j = 0; j < 4; ++j)
#pragma unroll
        for (int r = 0; r < 4; ++r)
          red[(wm + i * 16 + lq * 4 + r) * 128 + wn + j * 16 + lr] =
              acc[i][j][r];
  }
  __syncthreads();
  if (g == 0) {
#pragma unroll
    for (int i = 0; i < 4; ++i) {
      const int row = bm + wm + i * 16 + lq * 4;
#pragma unroll
      for (int j = 0; j < 4; ++j) {
        const int col = bn + wn + j * 16 + lr;
        const float bcol = bias[col];
#pragma unroll
        for (int r = 0; r < 4; ++r) {
          const size_t idx = (size_t)(row + r) * Nn + col;
          const float v = acc[i][j][r] +
                          red[(wm + i * 16 + lq * 4 + r) * 128 + wn + j * 16 + lr];
          dout[idx] = gelu_f(v + bcol) + resid[idx];
        }
      }
    }
  }
}

// ---------------- 64x128xBK64 GEMM, dbuf + XCD-locality swizzle --------------
template <int EPI>
__global__ __launch_bounds__(256, 4) void gemm64_bt(const bf16_t* __restrict__ A,
                                                    const bf16_t* __restrict__ W,
                                                    float* __restrict__ Cf,
                                                    const float* __restrict__ bias,
                                                    const float* __restrict__ resid,
                                                    int M, int Nn, int K) {
  __shared__ alignas(16) bf16_t As[2][2 * 64 * 32];
  __shared__ alignas(16) bf16_t Bs[2][2 * 128 * 32];
  const int t = threadIdx.x;
  const int lane = t & 63;
  const int w = t >> 6;
  const int lin = blockIdx.x + 8 * blockIdx.y;
  const int bm = ((lin & 7) * 8 + (lin >> 6)) * 64;
  const int bn = ((lin >> 3) & 7) * 128;
  const int wm = (w >> 1) * 32;
  const int wn = (w & 1) * 64;
  const int lr = lane & 15;
  const int lq = lane >> 4;
  f32x4 acc[2][4] = {};
  const bf16_t* Ap[2];
  const bf16_t* Bp[4];
#pragma unroll
  for (int c = 0; c < 2; ++c) {
    const int flat = c * 256 + t;
    const int p = flat >> 8;
    const int r = (flat >> 2) & 63;
    const int q = flat & 3;
    Ap[c] = A + (size_t)(bm + r) * K + p * 32 + q * 8;
  }
#pragma unroll
  for (int c = 0; c < 4; ++c) {
    const int flat = c * 256 + t;
    const int p = flat >> 9;
    const int r = (flat >> 2) & 127;
    const int q = flat & 3;
    Bp[c] = W + (size_t)(bn + r) * K + p * 32 + q * 8;
  }
#pragma unroll
  for (int c = 0; c < 2; ++c) async_copy16(Ap[c], &As[0][(c * 256 + t) * 8]);
#pragma unroll
  for (int c = 0; c < 4; ++c) async_copy16(Bp[c], &Bs[0][(c * 256 + t) * 8]);
  int buf = 0;
  for (int k0 = 0; k0 < K; k0 += 64) {
    __syncthreads();
    const int nb = buf ^ 1;
    if (k0 + 64 < K) {
#pragma unroll
      for (int c = 0; c < 2; ++c)
        async_copy16(Ap[c] + k0 + 64, &As[nb][(c * 256 + t) * 8]);
#pragma unroll
      for (int c = 0; c < 4; ++c)
        async_copy16(Bp[c] + k0 + 64, &Bs[nb][(c * 256 + t) * 8]);
    }
#pragma unroll
    for (int half = 0; half < 2; ++half) {
      const bf16_t* Ash = &As[buf][half * 2048];
      const bf16_t* Bsh = &Bs[buf][half * 4096];
      bf16x8 af[2], bfr[4];
#pragma unroll
      for (int i = 0; i < 2; ++i)
        af[i] = *(const bf16x8*)&Ash[(wm + i * 16 + lr) * 32 + lq * 8];
#pragma unroll
      for (int j = 0; j < 4; ++j)
        bfr[j] = *(const bf16x8*)&Bsh[(wn + j * 16 + lr) * 32 + lq * 8];
#pragma unroll
      for (int i = 0; i < 2; ++i)
#pragma unroll
        for (int j = 0; j < 4; ++j)
          acc[i][j] = MFMA16(af[i], bfr[j], acc[i][j]);
    }
    buf = nb;
  }
#pragma unroll
  for (int i = 0; i < 2; ++i) {
    const int row = bm + wm + i * 16 + lq * 4;
#pragma unroll
    for (int j = 0; j < 4; ++j) {
      const int col = bn + wn + j * 16 + lr;
      float bcol = bias[col];
#pragma unroll
      for (int r = 0; r < 4; ++r) {
        size_t idx = (size_t)(row + r) * Nn + col;
        float vv = acc[i][j][r];
        if (EPI == 1)
          Cf[idx] = vv + bcol + resid[idx];
        else
          Cf[idx] = gelu_f(vv + bcol) + resid[idx];
      }
    }
  }
}

// ---------------- fused QKV GEMM (BK32 dbuf); Q pre-scaled, V transposed -----
__global__ __launch_bounds__(256, 4) void gemm_qkv(const bf16_t* __restrict__ A,
                                                   const bf16_t* __restrict__ W0,
                                                   const bf16_t* __restrict__ W1,
                                                   const bf16_t* __restrict__ W2,
                                                   bf16_t* __restrict__ C0,
                                                   bf16_t* __restrict__ C1,
                                                   bf16_t* __restrict__ vt) {
  const int z = blockIdx.z;
  const bf16_t* W = (z == 0) ? W0 : ((z == 1) ? W1 : W2);
  const float osc = (z == 0) ? 0.045084220027780106f : 1.0f;
  const int K = 1024, Nn = 1024;
  __shared__ alignas(16) bf16_t As[2][128 * 32];
  __shared__ alignas(16) bf16_t Bs[2][128 * 32];
  const int t = threadIdx.x;
  const int lane = t & 63;
  const int w = t >> 6;
  const int bm = blockIdx.y * 128;
  const int bn = blockIdx.x * 128;
  const int wm = (w >> 1) * 64;
  const int wn = (w & 1) * 64;
  const int lr = lane & 15;
  const int lq = lane >> 4;
  f32x4 acc[4][4] = {};
  const bf16_t* Ap[2];
  const bf16_t* Bp[2];
#pragma unroll
  for (int c = 0; c < 2; ++c) {
    const int flat = c * 256 + t;
    const int r = flat >> 2;
    const int q = flat & 3;
    Ap[c] = A + (size_t)(bm + r) * K + q * 8;
    Bp[c] = W + (size_t)(bn + r) * K + q * 8;
  }
#pragma unroll
  for (int c = 0; c < 2; ++c) {
    async_copy16(Ap[c], &As[0][(c * 256 + t) * 8]);
    async_copy16(Bp[c], &Bs[0][(c * 256 + t) * 8]);
  }
  int buf = 0;
  for (int k0 = 0; k0 < K; k0 += 32) {
    __syncthreads();
    const int nb = buf ^ 1;
    if (k0 + 32 < K) {
#pragma unroll
      for (int c = 0; c < 2; ++c) {
        async_copy16(Ap[c] + k0 + 32, &As[nb][(c * 256 + t) * 8]);
        async_copy16(Bp[c] + k0 + 32, &Bs[nb][(c * 256 + t) * 8]);
      }
    }
    bf16x8 af[4], bfr[4];
#pragma unroll
    for (int i = 0; i < 4; ++i)
      af[i] = *(const bf16x8*)&As[buf][(wm + i * 16 + lr) * 32 + lq * 8];
#pragma unroll
    for (int j = 0; j < 4; ++j)
      bfr[j] = *(const bf16x8*)&Bs[buf][(wn + j * 16 + lr) * 32 + lq * 8];
#pragma unroll
    for (int i = 0; i < 4; ++i)
#pragma unroll
      for (int j = 0; j < 4; ++j)
        acc[i][j] = MFMA16(af[i], bfr[j], acc[i][j]);
    buf = nb;
  }
  if (z == 2) {
    // V transposed: vt[((b*16 + col/64)*64 + col%64)*2048 + n], quad = 4 n's
#pragma unroll
    for (int i = 0; i < 4; ++i) {
      const int row0 = bm + wm + i * 16 + lq * 4;  // n index base
      const int b = row0 >> 11;
      const int n = row0 & 2047;
#pragma unroll
      for (int j = 0; j < 4; ++j) {
        const int col = bn + wn + j * 16 + lr;  // global d (h*64 + dloc)
        bf16x4 pv;
#pragma unroll
        for (int r = 0; r < 4; ++r) pv[r] = (bf16_t)acc[i][j][r];
        *(bf16x4*)&vt[((size_t)(b * 16 + (col >> 6)) * 64 + (col & 63)) * 2048 + n] = pv;
      }
    }
  } else {
    bf16_t* Cb = (z == 0) ? C0 : C1;
#pragma unroll
    for (int i = 0; i < 4; ++i) {
      const int row = bm + wm + i * 16 + lq * 4;
#pragma unroll
      for (int j = 0; j < 4; ++j) {
        const int col = bn + wn + j * 16 + lr;
#pragma unroll
        for (int r = 0; r < 4; ++r)
          Cb[(size_t)(row + r) * Nn + col] = (bf16_t)(acc[i][j][r] * osc);
      }
    }
  }
}

// ---------------- flash attention v13: 8-wave blocks, dbuf, fused norm -------
// Grid (16 q-tiles, 32 bh), 512 threads / 8 waves, 2 blocks/CU -> 16
// waves/CU (4/SIMD) -- double v11's TLP, which was the v11 limiter (latency
// visible: Mfma 26% / VALU 40% / HBM 19%, nothing saturated, 8 waves/CU).
// Each wave owns 16 q-rows (exactly one u-slice of v11's math: sc[4],
// of[4], pf[2]); per-tile reuse stays 128 rows/staged tile (unlike a
// q-split). Staging is 2 async_copy16/thread/iter; simple dbuf
// __syncthreads loop (compile-time buffer indices -- v12's rotating 3-buf
// cost +32 VGPR of addr math and regressed). setprio(1) around MFMA
// clusters (m191: +4-7% attn, blocks progress independently).
__global__ __launch_bounds__(512, 2) void flash_attn(const bf16_t* __restrict__ q,
                                                     const bf16_t* __restrict__ k,
                                                     const bf16_t* __restrict__ vt,
                                                     bf16_t* __restrict__ attn) {
  __shared__ alignas(16) bf16_t Ks[2][64 * 64];
  __shared__ alignas(16) bf16_t Vs[2][64 * 64];
  const int t = threadIdx.x;   // 0..511
  const int lane = t & 63;
  const int w = t >> 6;        // wave 0..7, owns q-rows w*16..w*16+15
  const int lr = lane & 15;
  const int lq = lane >> 4;
  const int qt = blockIdx.x;   // query tile 0..15 (128 wide)
  const int bh = blockIdx.y;   // b*16+h
  const int b = bh >> 4;
  const int h = bh & 15;
  const size_t rowbase = (size_t)b * 2048;
  const int hcol = h * 64;
  const bf16_t* vtp = vt + (size_t)bh * 64 * 2048;

  bf16x8 qf0, qf1;
  {
    size_t qrow = rowbase + qt * 128 + w * 16 + lr;
    const bf16_t* qp = q + qrow * 1024 + hcol + lq * 8;
    qf0 = *(const bf16x8*)qp;
    qf1 = *(const bf16x8*)(qp + 32);
  }
  f32x4 of[4] = {};
  float lsum = 0.0f;

  // one 16B chunk per thread per tile (512 thr x 16B = 8KB = one 64x64 tile)
  const int sr = t >> 3;            // row 0..63
  const int sc = (t & 7) ^ (sr & 7);  // pre-swizzled 8-elem slot

  {
    async_copy16(k + (rowbase + sr) * 1024 + hcol + sc * 8, &Ks[0][t * 8]);
    async_copy16(vtp + (size_t)sr * 2048 + sc * 8, &Vs[0][t * 8]);
  }
  int buf = 0;
  for (int i = 0; i < 32; ++i) {
    __syncthreads();
    const int nb = buf ^ 1;
    if (i + 1 < 32) {
      const int ktn = i + 1;
      async_copy16(k + (rowbase + ktn * 64 + sr) * 1024 + hcol + sc * 8,
                   &Ks[nb][t * 8]);
      async_copy16(vtp + (size_t)sr * 2048 + ktn * 64 + sc * 8, &Vs[nb][t * 8]);
    }
    // ---- QK^T: scv[s][r] = S[k=16s+4*lq+r][q = qt*128 + w*16 + lr] ----
    f32x4 scv[4];
    __builtin_amdgcn_s_setprio(1);
#pragma unroll
    for (int s = 0; s < 4; ++s) {
      const int r2 = s * 16 + lr;
      bf16x8 kf0 = *(const bf16x8*)&Ks[buf][r2 * 64 + ((lq) ^ (r2 & 7)) * 8];
      bf16x8 kf1 = *(const bf16x8*)&Ks[buf][r2 * 64 + ((4 + lq) ^ (r2 & 7)) * 8];
      f32x4 c = {};
      c = MFMA16(kf0, qf0, c);
      c = MFMA16(kf1, qf1, c);
      scv[s] = c;
    }
    __builtin_amdgcn_s_setprio(0);
    // ---- exp, row-sum, in-register transpose into B-fragments ----
    float e[4][4];
#pragma unroll
    for (int s = 0; s < 4; ++s)
#pragma unroll
      for (int r = 0; r < 4; ++r) {
        e[s][r] = EXP2F(scv[s][r]);
        lsum += e[s][r];
      }
    unsigned w0[4], w1[4];
#pragma unroll
    for (int s = 0; s < 4; ++s) {
      w0[s] = cvt_pk_bf16(e[s][0], e[s][1]);
      w1[s] = cvt_pk_bf16(e[s][2], e[s][3]);
    }
    bf16x8 pf[2];
#pragma unroll
    for (int half = 0; half < 2; ++half) {
      unsigned a0 = w0[2 * half], a1 = w0[2 * half + 1];
      unsigned b0 = w1[2 * half], b1 = w1[2 * half + 1];
      plane32_swap(a0, a1);
      plane16_swap(a0, a1);
      plane32_swap(b0, b1);
      plane16_swap(b0, b1);
      union {
        bf16x8 v;
        unsigned wd[4];
      } pu;
      pu.wd[0] = a0;
      pu.wd[1] = b0;
      pu.wd[2] = a1;
      pu.wd[3] = b1;
      pf[half] = pu.v;
    }
    // ---- PV: O^T[d][q] += V^T (A) x P (B) ----
    __builtin_amdgcn_s_setprio(1);
#pragma unroll
    for (int d = 0; d < 4; ++d) {
      const int rv = d * 16 + lr;
      bf16x8 vf0 = *(const bf16x8*)&Vs[buf][rv * 64 + ((lq) ^ (rv & 7)) * 8];
      bf16x8 vf1 = *(const bf16x8*)&Vs[buf][rv * 64 + ((4 + lq) ^ (rv & 7)) * 8];
      of[d] = MFMA16(vf0, pf[0], of[d]);
      of[d] = MFMA16(vf1, pf[1], of[d]);
    }
    __builtin_amdgcn_s_setprio(0);
    buf = nb;
  }
  // of[d][r] = O^T[dglob = d*16 + lq*4 + r][q = qt*128 + w*16 + lr]
  // normalize by the full row-sum (reduced across lq groups) and store attn
  float l = lsum;
  l += __shfl_xor(l, 16);
  l += __shfl_xor(l, 32);
  const float inv = 1.0f / l;
  const size_t qrow = rowbase + qt * 128 + w * 16 + lr;
#pragma unroll
  for (int d = 0; d < 4; ++d) {
    bf16x4 pv;
#pragma unroll
    for (int r = 0; r < 4; ++r) pv[r] = (bf16_t)(of[d][r] * inv);
    *(bf16x4*)&attn[qrow * 1024 + hcol + d * 16 + lq * 4] = pv;
  }
}

extern "C" void kernel_launch(void* const* d_in, const int* in_sizes, int n_in,
                              void* d_out, int out_size, void* d_ws, size_t ws_size,
                              hipStream_t stream) {
  (void)in_sizes;
  (void)n_in;
  (void)out_size;
  (void)ws_size;
  const float* x = (const float*)d_in[0];
  const float* la1g = (const float*)d_in[1];
  const float* la1b = (const float*)d_in[2];
  const float* Wq = (const float*)d_in[3];
  const float* Wk = (const float*)d_in[4];
  const float* Wv = (const float*)d_in[5];
  const float* Wo = (const float*)d_in[6];
  const float* bo = (const float*)d_in[7];
  const float* la2g = (const float*)d_in[8];
  const float* la2b = (const float*)d_in[9];
  const float* W1 = (const float*)d_in[10];
  const float* b1 = (const float*)d_in[11];
  const float* W2 = (const float*)d_in[12];
  const float* b2 = (const float*)d_in[13];
  char* ws = (char*)d_ws;
  const size_t MB = (size_t)1 << 20;
  bf16_t* wq_b = (bf16_t*)(ws + 0 * MB);
  bf16_t* wk_b = (bf16_t*)(ws + 2 * MB);
  bf16_t* wv_b = (bf16_t*)(ws + 4 * MB);
  bf16_t* wo_b = (bf16_t*)(ws + 6 * MB);
  bf16_t* w1_b = (bf16_t*)(ws + 8 * MB);
  bf16_t* w2_b = (bf16_t*)(ws + 16 * MB);
  bf16_t* hbuf = (bf16_t*)(ws + 24 * MB);  // ln1 out, QKV input
  bf16_t* qb = (bf16_t*)(ws + 32 * MB);
  bf16_t* kb = (bf16_t*)(ws + 40 * MB);
  bf16_t* vt = (bf16_t*)(ws + 48 * MB);    // V written transposed by QKV
  bf16_t* attn = (bf16_t*)(ws + 56 * MB);
  float* outb = (float*)(ws + 64 * MB);    // 16 MB fp32
  bf16_t* h2 = (bf16_t*)(ws + 80 * MB);    // 8 MB
  bf16_t* m1 = (bf16_t*)(ws + 88 * MB);    // 32 MB (88-120)
  float* dout = (float*)d_out;

  cvt_all<<<dim3(1024, 12), 256, 0, stream>>>(Wq, Wk, Wv, Wo, W1, W2, wq_b,
                                              wk_b, wv_b, wo_b, w1_b, w2_b);
  ln_k<<<4096, 256, 0, stream>>>(x, la1g, la1b, hbuf);
  gemm_qkv<<<dim3(8, 32, 3), 256, 0, stream>>>(hbuf, wq_b, wk_b, wv_b, qb, kb, vt);
  flash_attn<<<dim3(16, 32), 512, 0, stream>>>(qb, kb, vt, attn);
  gemm64_bt<1><<<dim3(8, 64), 256, 0, stream>>>(attn, wo_b, outb, bo, x, 4096, 1024, 1024);
  ln_k<<<4096, 256, 0, stream>>>(outb, la2g, la2b, h2);
  gemm256<2><<<256, 512, 0, stream>>>(h2, w1_b, m1, b1, 4096, 1024);
  gemm_sk2<<<dim3(8, 32), 512, 0, stream>>>(m1, w2_b, b2, outb, dout);
}

// Round 10
// 312.302 us; speedup vs baseline: 1.0366x; 1.0188x over previous
//
#include <hip/hip_runtime.h>
#include <hip/hip_bf16.h>

typedef __bf16 bf16_t;
typedef __bf16 bf16x4 __attribute__((ext_vector_type(4)));
typedef __bf16 bf16x8 __attribute__((ext_vector_type(8)));
typedef float f32x4 __attribute__((ext_vector_type(4)));
typedef unsigned uintx2 __attribute__((ext_vector_type(2)));

#define MFMA16(a, b, c) __builtin_amdgcn_mfma_f32_16x16x32_bf16((a), (b), (c), 0, 0, 0)

#if defined(__has_builtin) && __has_builtin(__builtin_amdgcn_exp2f)
#define EXP2F(x) __builtin_amdgcn_exp2f(x)
#else
#define EXP2F(x) exp2f(x)
#endif

__device__ __forceinline__ void async_copy16(const void* g, void* l) {
#if defined(__has_builtin) && __has_builtin(__builtin_amdgcn_global_load_lds)
  __builtin_amdgcn_global_load_lds((__attribute__((address_space(1))) void*)g,
                                   (__attribute__((address_space(3))) void*)l, 16, 0, 0);
#else
  *(bf16x8*)l = *(const bf16x8*)g;
#endif
}

// tanh-approx GELU in sigmoid form: x*sigmoid(2c(x+0.044715x^3)); |err|<~3e-3
__device__ __forceinline__ float gelu_f(float x) {
  float u = x * (1.5957691216057308f + 0.07135481283f * x * x);
  return x / (1.0f + __expf(-u));
}

// pack two f32 -> one u32 of 2 bf16 (low = lo)
__device__ __forceinline__ unsigned cvt_pk_bf16(float lo, float hi) {
  unsigned r;
  asm("v_cvt_pk_bf16_f32 %0, %1, %2" : "=v"(r) : "v"(lo), "v"(hi));
  return r;
}

// pair swap: a' = {a[0:31], b[0:31]}, b' = {a[32:63], b[32:63]}
__device__ __forceinline__ void plane32_swap(unsigned& a, unsigned& b) {
#if defined(__has_builtin) && __has_builtin(__builtin_amdgcn_permlane32_swap)
  uintx2 r = __builtin_amdgcn_permlane32_swap(a, b, false, false);
  a = r[0];
  b = r[1];
#else
  const int lane = threadIdx.x & 63;
  unsigned as = (unsigned)__shfl_xor((int)a, 32);
  unsigned bs = (unsigned)__shfl_xor((int)b, 32);
  unsigned na = (lane < 32) ? a : bs;
  unsigned nb = (lane < 32) ? as : b;
  a = na;
  b = nb;
#endif
}

// per-16 swap within each half: a' = {a@0,b@0,a@2,b@2}, b' = {a@1,b@1,a@3,b@3}
__device__ __forceinline__ void plane16_swap(unsigned& a, unsigned& b) {
#if defined(__has_builtin) && __has_builtin(__builtin_amdgcn_permlane16_swap)
  uintx2 r = __builtin_amdgcn_permlane16_swap(a, b, false, false);
  a = r[0];
  b = r[1];
#else
  const int lane = threadIdx.x & 63;
  unsigned as = (unsigned)__shfl_xor((int)a, 16);
  unsigned bs = (unsigned)__shfl_xor((int)b, 16);
  unsigned na = (lane & 16) ? bs : a;
  unsigned nb = (lane & 16) ? b : as;
  a = na;
  b = nb;
#endif
}

// -------- merged: all weight fp32->bf16 converts + layernorm1, ONE dispatch --
// blocks 0..12287: cvt planes (12 x 1024 blocks, 1M elems each);
// blocks 12288..16383: LN rows of x -> hbuf.
__global__ __launch_bounds__(256) void cvt_ln(const float* __restrict__ sq,
                                              const float* __restrict__ sk,
                                              const float* __restrict__ sv,
                                              const float* __restrict__ so,
                                              const float* __restrict__ s1,
                                              const float* __restrict__ s2,
                                              bf16_t* __restrict__ dq,
                                              bf16_t* __restrict__ dk,
                                              bf16_t* __restrict__ dv,
                                              bf16_t* __restrict__ do_,
                                              bf16_t* __restrict__ d1,
                                              bf16_t* __restrict__ d2,
                                              const float* __restrict__ x,
                                              const float* __restrict__ g,
                                              const float* __restrict__ b,
                                              bf16_t* __restrict__ o) {
  const int bid = blockIdx.x;
  const int t = threadIdx.x;
  if (bid < 12288) {
    const int y = bid >> 10;
    const int bx = bid & 1023;
    const float* s;
    bf16_t* d;
    if (y < 4) {
      s = (y == 0) ? sq : (y == 1) ? sk : (y == 2) ? sv : so;
      d = (y == 0) ? dq : (y == 1) ? dk : (y == 2) ? dv : do_;
    } else if (y < 8) {
      s = s1 + (size_t)(y - 4) * 1048576;
      d = d1 + (size_t)(y - 4) * 1048576;
    } else {
      s = s2 + (size_t)(y - 8) * 1048576;
      d = d2 + (size_t)(y - 8) * 1048576;
    }
    int i = (bx * 256 + t) * 4;
    float4 f = *(const float4*)(s + i);
    d[i + 0] = (bf16_t)f.x;
    d[i + 1] = (bf16_t)f.y;
    d[i + 2] = (bf16_t)f.z;
    d[i + 3] = (bf16_t)f.w;
  } else {
    __shared__ float red[8];
    const size_t row = bid - 12288;
    float4 xv = ((const float4*)(x + row * 1024))[t];
    float s = xv.x + xv.y + xv.z + xv.w;
    float s2v = xv.x * xv.x + xv.y * xv.y + xv.z * xv.z + xv.w * xv.w;
#pragma unroll
    for (int off = 1; off < 64; off <<= 1) {
      s += __shfl_xor(s, off);
      s2v += __shfl_xor(s2v, off);
    }
    if ((t & 63) == 0) {
      red[t >> 6] = s;
      red[4 + (t >> 6)] = s2v;
    }
    __syncthreads();
    s = red[0] + red[1] + red[2] + red[3];
    s2v = red[4] + red[5] + red[6] + red[7];
    const float mu = s * (1.0f / 1024.0f);
    const float rstd = rsqrtf(s2v * (1.0f / 1024.0f) - mu * mu + 1e-5f);
    float4 gv = ((const float4*)g)[t];
    float4 bv = ((const float4*)b)[t];
    bf16_t* op = o + row * 1024 + t * 4;
    op[0] = (bf16_t)((xv.x - mu) * rstd * gv.x + bv.x);
    op[1] = (bf16_t)((xv.y - mu) * rstd * gv.y + bv.y);
    op[2] = (bf16_t)((xv.z - mu) * rstd * gv.z + bv.z);
    op[3] = (bf16_t)((xv.w - mu) * rstd * gv.w + bv.w);
  }
}

// ---------------- layernorm over 1024 cols, one block per row ----------------
__global__ __launch_bounds__(256) void ln_k(const float* __restrict__ x,
                                            const float* __restrict__ g,
                                            const float* __restrict__ b,
                                            bf16_t* __restrict__ o) {
  __shared__ float red[8];
  const int t = threadIdx.x;
  const size_t row = blockIdx.x;
  float4 xv = ((const float4*)(x + row * 1024))[t];
  float s = xv.x + xv.y + xv.z + xv.w;
  float s2 = xv.x * xv.x + xv.y * xv.y + xv.z * xv.z + xv.w * xv.w;
#pragma unroll
  for (int off = 1; off < 64; off <<= 1) {
    s += __shfl_xor(s, off);
    s2 += __shfl_xor(s2, off);
  }
  if ((t & 63) == 0) {
    red[t >> 6] = s;
    red[4 + (t >> 6)] = s2;
  }
  __syncthreads();
  s = red[0] + red[1] + red[2] + red[3];
  s2 = red[4] + red[5] + red[6] + red[7];
  const float mu = s * (1.0f / 1024.0f);
  const float rstd = rsqrtf(s2 * (1.0f / 1024.0f) - mu * mu + 1e-5f);
  float4 gv = ((const float4*)g)[t];
  float4 bv = ((const float4*)b)[t];
  bf16_t* op = o + row * 1024 + t * 4;
  op[0] = (bf16_t)((xv.x - mu) * rstd * gv.x + bv.x);
  op[1] = (bf16_t)((xv.y - mu) * rstd * gv.y + bv.y);
  op[2] = (bf16_t)((xv.z - mu) * rstd * gv.z + bv.z);
  op[3] = (bf16_t)((xv.w - mu) * rstd * gv.w + bv.w);
}

// ---------------- 256x256xBK64 GEMM, slab waves + per-phase interleave -------
// Slab geometry (measured-best read economy: 24 ds_read / 64 MFMA / wave):
// 8 waves 2Mx4N, per-wave 128x64 output slab, B frags cached in regs once
// per K-tile. NEW: the K-tile is split into 4 {ds_read pair -> setprio ->
// 16 MFMA -> barrier} phases with the 4 half-tile stages distributed one per
// phase (issue order B0@top,B1,A0,A1 = consumption order), and ONE counted
// vmcnt(2) per tile issued AFTER the next B0 stage -- never a full drain.
// This is m196/m201's fine interleave applied for the first time to the
// geometry that is not LDS-BW-bound (earlier 8-phase attempts used the
// 48-read quadrant geometry and were LDS-limited).
template <int EPI>
__global__ __launch_bounds__(512, 2) void gemm256(const bf16_t* __restrict__ A,
                                                  const bf16_t* __restrict__ W,
                                                  bf16_t* __restrict__ Cb,
                                                  const float* __restrict__ bias,
                                                  int Nn, int K) {
  __shared__ alignas(16) bf16_t As[2][2 * 128 * 64];
  __shared__ alignas(16) bf16_t Bs[2][2 * 128 * 64];
  const int t = threadIdx.x;
  const int lane = t & 63;
  const int w = t >> 6;
  // bijective XCD swizzle (gridDim.x % 8 == 0)
  const int cpx = gridDim.x >> 3;
  const int bid = blockIdx.x;
  const int swz = (bid & 7) * cpx + (bid >> 3);
  const int nbx = Nn >> 8;
  const int bm = (swz / nbx) * 256;
  const int bn = (swz % nbx) * 256;
  const int wmh = w >> 2;  // A half-tile this wave consumes (rows wmh*128..)
  const int wnq = w & 3;   // 64-col slice
  const int lr = lane & 15;
  const int lq = lane >> 4;
  f32x4 acc[8][4] = {};
  // swizzled ds_read base offsets; frag (i or j) adds i*1024 (16 rows * 64)
  int abase[2], bbase[2];
#pragma unroll
  for (int ks = 0; ks < 2; ++ks) {
    const int sw = ((ks * 4 + lq) ^ (lr & 7)) * 8;
    abase[ks] = wmh * 8192 + lr * 64 + sw;
    bbase[ks] = (wnq >> 1) * 8192 + (wnq & 1) * 4096 + lr * 64 + sw;
  }
  // per-thread staging pointers (pre-swizzled global source), linear LDS dst
  const bf16_t* apt[2][2];
  const bf16_t* bpt[2][2];
  int ldst[2];
#pragma unroll
  for (int c = 0; c < 2; ++c) {
    const int flat = c * 512 + t;        // 16B chunk 0..1023 within a half
    const int r = flat >> 3;             // row within half 0..127
    const int q = (flat & 7) ^ (r & 7);  // pre-swizzled 8-elem slot
    ldst[c] = flat * 8;
#pragma unroll
    for (int h = 0; h < 2; ++h) {
      apt[h][c] = A + (size_t)(bm + h * 128 + r) * K + q * 8;
      bpt[h][c] = W + (size_t)(bn + h * 128 + r) * K + q * 8;
    }
  }
  const int NT = K >> 6;
  // prologue: stage tile 0 (consumption order B0,B1,A0,A1)
#pragma unroll
  for (int c = 0; c < 2; ++c) async_copy16(bpt[0][c], &Bs[0][ldst[c]]);
#pragma unroll
  for (int c = 0; c < 2; ++c) async_copy16(bpt[1][c], &Bs[0][8192 + ldst[c]]);
#pragma unroll
  for (int c = 0; c < 2; ++c) async_copy16(apt[0][c], &As[0][ldst[c]]);
#pragma unroll
  for (int c = 0; c < 2; ++c) async_copy16(apt[1][c], &As[0][8192 + ldst[c]]);
  for (int kt = 0; kt < NT; ++kt) {
    const bf16_t* Ab = As[kt & 1];
    const bf16_t* Bb = Bs[kt & 1];
    bf16_t* Asn = As[(kt & 1) ^ 1];
    bf16_t* Bsn = Bs[(kt & 1) ^ 1];
    const int nk = (kt + 1) << 6;
    const bool pre = (kt + 1 < NT);
    // stage B0(kt+1) first, then counted wait: tile kt's 8 loads retired,
    // B0's 2 stay in flight
    if (pre) {
#pragma unroll
      for (int c = 0; c < 2; ++c) async_copy16(bpt[0][c] + nk, Bsn + ldst[c]);
      asm volatile("s_waitcnt vmcnt(2)" ::: "memory");
    } else {
      asm volatile("s_waitcnt vmcnt(0)" ::: "memory");
    }
    __builtin_amdgcn_s_barrier();  // tile kt published to all waves
    // B fragments once per K-tile (regs, live across all 4 phases)
    bf16x8 bfr[4][2];
#pragma unroll
    for (int j = 0; j < 4; ++j)
#pragma unroll
      for (int ks = 0; ks < 2; ++ks)
        bfr[j][ks] = *(const bf16x8*)&Bb[bbase[ks] + j * 1024];
    // ---- phase 0: m-pair 0 ----
    {
      bf16x8 af0 = *(const bf16x8*)&Ab[abase[0]];
      bf16x8 af0b = *(const bf16x8*)&Ab[abase[1]];
      bf16x8 af1 = *(const bf16x8*)&Ab[abase[0] + 1024];
      bf16x8 af1b = *(const bf16x8*)&Ab[abase[1] + 1024];
      __builtin_amdgcn_s_setprio(1);
#pragma unroll
      for (int j = 0; j < 4; ++j) {
        acc[0][j] = MFMA16(af0, bfr[j][0], acc[0][j]);
        acc[0][j] = MFMA16(af0b, bfr[j][1], acc[0][j]);
        acc[1][j] = MFMA16(af1, bfr[j][0], acc[1][j]);
        acc[1][j] = MFMA16(af1b, bfr[j][1], acc[1][j]);
      }
      __builtin_amdgcn_s_setprio(0);
    }
    if (pre) {
#pragma unroll
      for (int c = 0; c < 2; ++c)
        async_copy16(bpt[1][c] + nk, Bsn + 8192 + ldst[c]);
    }
    __builtin_amdgcn_s_barrier();
    // ---- phase 1: m-pair 1 ----
    {
      bf16x8 af0 = *(const bf16x8*)&Ab[abase[0] + 2 * 1024];
      bf16x8 af0b = *(const bf16x8*)&Ab[abase[1] + 2 * 1024];
      bf16x8 af1 = *(const bf16x8*)&Ab[abase[0] + 3 * 1024];
      bf16x8 af1b = *(const bf16x8*)&Ab[abase[1] + 3 * 1024];
      __builtin_amdgcn_s_setprio(1);
#pragma unroll
      for (int j = 0; j < 4; ++j) {
        acc[2][j] = MFMA16(af0, bfr[j][0], acc[2][j]);
        acc[2][j] = MFMA16(af0b, bfr[j][1], acc[2][j]);
        acc[3][j] = MFMA16(af1, bfr[j][0], acc[3][j]);
        acc[3][j] = MFMA16(af1b, bfr[j][1], acc[3][j]);
      }
      __builtin_amdgcn_s_setprio(0);
    }
    if (pre) {
#pragma unroll
      for (int c = 0; c < 2; ++c) async_copy16(apt[0][c] + nk, Asn + ldst[c]);
    }
    __builtin_amdgcn_s_barrier();
    // ---- phase 2: m-pair 2 ----
    {
      bf16x8 af0 = *(const bf16x8*)&Ab[abase[0] + 4 * 1024];
      bf16x8 af0b = *(const bf16x8*)&Ab[abase[1] + 4 * 1024];
      bf16x8 af1 = *(const bf16x8*)&Ab[abase[0] + 5 * 1024];
      bf16x8 af1b = *(const bf16x8*)&Ab[abase[1] + 5 * 1024];
      __builtin_amdgcn_s_setprio(1);
#pragma unroll
      for (int j = 0; j < 4; ++j) {
        acc[4][j] = MFMA16(af0, bfr[j][0], acc[4][j]);
        acc[4][j] = MFMA16(af0b, bfr[j][1], acc[4][j]);
        acc[5][j] = MFMA16(af1, bfr[j][0], acc[5][j]);
        acc[5][j] = MFMA16(af1b, bfr[j][1], acc[5][j]);
      }
      __builtin_amdgcn_s_setprio(0);
    }
    if (pre) {
#pragma unroll
      for (int c = 0; c < 2; ++c)
        async_copy16(apt[1][c] + nk, Asn + 8192 + ldst[c]);
    }
    __builtin_amdgcn_s_barrier();
    // ---- phase 3: m-pair 3 ----
    {
      bf16x8 af0 = *(const bf16x8*)&Ab[abase[0] + 6 * 1024];
      bf16x8 af0b = *(const bf16x8*)&Ab[abase[1] + 6 * 1024];
      bf16x8 af1 = *(const bf16x8*)&Ab[abase[0] + 7 * 1024];
      bf16x8 af1b = *(const bf16x8*)&Ab[abase[1] + 7 * 1024];
      __builtin_amdgcn_s_setprio(1);
#pragma unroll
      for (int j = 0; j < 4; ++j) {
        acc[6][j] = MFMA16(af0, bfr[j][0], acc[6][j]);
        acc[6][j] = MFMA16(af0b, bfr[j][1], acc[6][j]);
        acc[7][j] = MFMA16(af1, bfr[j][0], acc[7][j]);
        acc[7][j] = MFMA16(af1b, bfr[j][1], acc[7][j]);
      }
      __builtin_amdgcn_s_setprio(0);
    }
    __builtin_amdgcn_s_barrier();
  }
#pragma unroll
  for (int i = 0; i < 8; ++i) {
    const int row = bm + wmh * 128 + i * 16 + lq * 4;
#pragma unroll
    for (int j = 0; j < 4; ++j) {
      const int col = bn + wnq * 64 + j * 16 + lr;
      const float bcol = (EPI >= 1) ? bias[col] : 0.0f;
#pragma unroll
      for (int r = 0; r < 4; ++r) {
        size_t idx = (size_t)(row + r) * Nn + col;
        float vv = acc[i][j][r];
        if (EPI == 2)
          Cb[idx] = (bf16_t)gelu_f(vv + bcol);
        else
          Cb[idx] = (bf16_t)(vv + bcol);
      }
    }
  }
}

// ---------------- W2 GEMM: in-block split-K + fused gelu/resid epilogue ------
__global__ __launch_bounds__(512, 2) void gemm_sk2(const bf16_t* __restrict__ A,
                                                   const bf16_t* __restrict__ W,
                                                   const float* __restrict__ bias,
                                                   const float* __restrict__ resid,
                                                   float* __restrict__ dout) {
  const int K = 4096, Nn = 1024;
  // [group][buf][ A(8192 elems) | B(8192 elems) ] = 128 KB
  __shared__ alignas(16) bf16_t AB[2][2][2 * 8192];
  const int t = threadIdx.x;
  const int tg = t & 255;       // thread id within group
  const int lane = t & 63;
  const int g = t >> 8;         // K-split group (0: lo half, 1: hi half)
  const int w = (t >> 6) & 3;   // wave within group
  const int lin = blockIdx.x + 8 * blockIdx.y;  // 0..255, XCD-friendly
  const int bm = ((lin & 7) * 4 + ((lin >> 6) & 3)) * 128;
  const int bn = ((lin >> 3) & 7) * 128;
  const int kbase = g * 2048;
  const int wm = (w >> 1) * 64;
  const int wn = (w & 1) * 64;
  const int lr = lane & 15;
  const int lq = lane >> 4;
  f32x4 acc[4][4] = {};
  // staging: pre-swizzled global source -> linear LDS (0-conflict pair)
  const bf16_t* apt[4];
  const bf16_t* bpt[4];
  int ldst[4];
#pragma unroll
  for (int c = 0; c < 4; ++c) {
    const int flat = c * 256 + tg;       // 16B chunk 0..1023
    const int r = flat >> 3;             // row 0..127
    const int q = (flat & 7) ^ (r & 7);  // pre-swizzled 8-elem slot
    ldst[c] = flat * 8;
    apt[c] = A + (size_t)(bm + r) * K + kbase + q * 8;
    bpt[c] = W + (size_t)(bn + r) * K + kbase + q * 8;
  }
  // swizzled ds_read base offsets ([128][64] tile, frag adds i*1024)
  int abase[2], bbase[2];
#pragma unroll
  for (int ks = 0; ks < 2; ++ks) {
    const int sw = ((ks * 4 + lq) ^ (lr & 7)) * 8;
    abase[ks] = (wm + lr) * 64 + sw;
    bbase[ks] = (wn + lr) * 64 + sw;
  }
#pragma unroll
  for (int c = 0; c < 4; ++c) {
    async_copy16(apt[c], &AB[g][0][ldst[c]]);
    async_copy16(bpt[c], &AB[g][0][8192 + ldst[c]]);
  }
  for (int kt = 0; kt < 32; ++kt) {
    __syncthreads();  // drains this buffer's loads (in flight one full iter)
    const int k0 = kt << 6;
    const int buf = kt & 1;
    if (kt + 1 < 32) {
#pragma unroll
      for (int c = 0; c < 4; ++c) {
        async_copy16(apt[c] + k0 + 64, &AB[g][buf ^ 1][ldst[c]]);
        async_copy16(bpt[c] + k0 + 64, &AB[g][buf ^ 1][8192 + ldst[c]]);
      }
    }
    const bf16_t* Ab = &AB[g][buf][0];
    const bf16_t* Bb = &AB[g][buf][8192];
    bf16x8 bfr[4][2];
#pragma unroll
    for (int j = 0; j < 4; ++j)
#pragma unroll
      for (int ks = 0; ks < 2; ++ks)
        bfr[j][ks] = *(const bf16x8*)&Bb[bbase[ks] + j * 1024];
#pragma unroll
    for (int i = 0; i < 4; ++i) {
      bf16x8 af0 = *(const bf16x8*)&Ab[abase[0] + i * 1024];
      bf16x8 af1 = *(const bf16x8*)&Ab[abase[1] + i * 1024];
#pragma unroll
      for (int j = 0; j < 4; ++j) {
        acc[i][j] = MFMA16(af0, bfr[j][0], acc[i][j]);
        acc[i][j] = MFMA16(af1, bfr[j][1], acc[i][j]);
      }
    }
  }
  // ---- in-block split-K reduction + fused epilogue ----
  __syncthreads();  // all LDS reads of the K-loop complete
  float* red = (float*)&AB[0][0][0];  // 64 KB of the 128 KB LDS
  if (g == 1) {
#pragma unroll
    for (int i = 0; i < 4; ++i)
#pragma unroll
      for (int j = 0; j < 4; ++j)
#pragma unroll
        for (int r = 0; r < 4; ++r)
          red[(wm + i * 16 + lq * 4 + r) * 128 + wn + j * 16 + lr] =
              acc[i][j][r];
  }
  __syncthreads();
  if (g == 0) {
#pragma unroll
    for (int i = 0; i < 4; ++i) {
      const int row = bm + wm + i * 16 + lq * 4;
#pragma unroll
      for (int j = 0; j < 4; ++j) {
        const int col = bn + wn + j * 16 + lr;
        const float bcol = bias[col];
#pragma unroll
        for (int r = 0; r < 4; ++r) {
          const size_t idx = (size_t)(row + r) * Nn + col;
          const float v = acc[i][j][r] +
                          red[(wm + i * 16 + lq * 4 + r) * 128 + wn + j * 16 + lr];
          dout[idx] = gelu_f(v + bcol) + resid[idx];
        }
      }
    }
  }
}

// ---------------- 64x128xBK64 GEMM, dbuf + XCD-locality swizzle --------------
template <int EPI>
__global__ __launch_bounds__(256, 4) void gemm64_bt(const bf16_t* __restrict__ A,
                                                    const bf16_t* __restrict__ W,
                                                    float* __restrict__ Cf,
                                                    const float* __restrict__ bias,
                                                    const float* __restrict__ resid,
                                                    int M, int Nn, int K) {
  __shared__ alignas(16) bf16_t As[2][2 * 64 * 32];
  __shared__ alignas(16) bf16_t Bs[2][2 * 128 * 32];
  const int t = threadIdx.x;
  const int lane = t & 63;
  const int w = t >> 6;
  const int lin = blockIdx.x + 8 * blockIdx.y;
  const int bm = ((lin & 7) * 8 + (lin >> 6)) * 64;
  const int bn = ((lin >> 3) & 7) * 128;
  const int wm = (w >> 1) * 32;
  const int wn = (w & 1) * 64;
  const int lr = lane & 15;
  const int lq = lane >> 4;
  f32x4 acc[2][4] = {};
  const bf16_t* Ap[2];
  const bf16_t* Bp[4];
#pragma unroll
  for (int c = 0; c < 2; ++c) {
    const int flat = c * 256 + t;
    const int p = flat >> 8;
    const int r = (flat >> 2) & 63;
    const int q = flat & 3;
    Ap[c] = A + (size_t)(bm + r) * K + p * 32 + q * 8;
  }
#pragma unroll
  for (int c = 0; c < 4; ++c) {
    const int flat = c * 256 + t;
    const int p = flat >> 9;
    const int r = (flat >> 2) & 127;
    const int q = flat & 3;
    Bp[c] = W + (size_t)(bn + r) * K + p * 32 + q * 8;
  }
#pragma unroll
  for (int c = 0; c < 2; ++c) async_copy16(Ap[c], &As[0][(c * 256 + t) * 8]);
#pragma unroll
  for (int c = 0; c < 4; ++c) async_copy16(Bp[c], &Bs[0][(c * 256 + t) * 8]);
  int buf = 0;
  for (int k0 = 0; k0 < K; k0 += 64) {
    __syncthreads();
    const int nb = buf ^ 1;
    if (k0 + 64 < K) {
#pragma unroll
      for (int c = 0; c < 2; ++c)
        async_copy16(Ap[c] + k0 + 64, &As[nb][(c * 256 + t) * 8]);
#pragma unroll
      for (int c = 0; c < 4; ++c)
        async_copy16(Bp[c] + k0 + 64, &Bs[nb][(c * 256 + t) * 8]);
    }
#pragma unroll
    for (int half = 0; half < 2; ++half) {
      const bf16_t* Ash = &As[buf][half * 2048];
      const bf16_t* Bsh = &Bs[buf][half * 4096];
      bf16x8 af[2], bfr[4];
#pragma unroll
      for (int i = 0; i < 2; ++i)
        af[i] = *(const bf16x8*)&Ash[(wm + i * 16 + lr) * 32 + lq * 8];
#pragma unroll
      for (int j = 0; j < 4; ++j)
        bfr[j] = *(const bf16x8*)&Bsh[(wn + j * 16 + lr) * 32 + lq * 8];
#pragma unroll
      for (int i = 0; i < 2; ++i)
#pragma unroll
        for (int j = 0; j < 4; ++j)
          acc[i][j] = MFMA16(af[i], bfr[j], acc[i][j]);
    }
    buf = nb;
  }
#pragma unroll
  for (int i = 0; i < 2; ++i) {
    const int row = bm + wm + i * 16 + lq * 4;
#pragma unroll
    for (int j = 0; j < 4; ++j) {
      const int col = bn + wn + j * 16 + lr;
      float bcol = bias[col];
#pragma unroll
      for (int r = 0; r < 4; ++r) {
        size_t idx = (size_t)(row + r) * Nn + col;
        float vv = acc[i][j][r];
        if (EPI == 1)
          Cf[idx] = vv + bcol + resid[idx];
        else
          Cf[idx] = gelu_f(vv + bcol) + resid[idx];
      }
    }
  }
}

// ---------------- fused QKV GEMM (BK32 dbuf); Q pre-scaled, V transposed -----
__global__ __launch_bounds__(256, 4) void gemm_qkv(const bf16_t* __restrict__ A,
                                                   const bf16_t* __restrict__ W0,
                                                   const bf16_t* __restrict__ W1,
                                                   const bf16_t* __restrict__ W2,
                                                   bf16_t* __restrict__ C0,
                                                   bf16_t* __restrict__ C1,
                                                   bf16_t* __restrict__ vt) {
  const int z = blockIdx.z;
  const bf16_t* W = (z == 0) ? W0 : ((z == 1) ? W1 : W2);
  const float osc = (z == 0) ? 0.045084220027780106f : 1.0f;
  const int K = 1024, Nn = 1024;
  __shared__ alignas(16) bf16_t As[2][128 * 32];
  __shared__ alignas(16) bf16_t Bs[2][128 * 32];
  const int t = threadIdx.x;
  const int lane = t & 63;
  const int w = t >> 6;
  const int bm = blockIdx.y * 128;
  const int bn = blockIdx.x * 128;
  const int wm = (w >> 1) * 64;
  const int wn = (w & 1) * 64;
  const int lr = lane & 15;
  const int lq = lane >> 4;
  f32x4 acc[4][4] = {};
  const bf16_t* Ap[2];
  const bf16_t* Bp[2];
#pragma unroll
  for (int c = 0; c < 2; ++c) {
    const int flat = c * 256 + t;
    const int r = flat >> 2;
    const int q = flat & 3;
    Ap[c] = A + (size_t)(bm + r) * K + q * 8;
    Bp[c] = W + (size_t)(bn + r) * K + q * 8;
  }
#pragma unroll
  for (int c = 0; c < 2; ++c) {
    async_copy16(Ap[c], &As[0][(c * 256 + t) * 8]);
    async_copy16(Bp[c], &Bs[0][(c * 256 + t) * 8]);
  }
  int buf = 0;
  for (int k0 = 0; k0 < K; k0 += 32) {
    __syncthreads();
    const int nb = buf ^ 1;
    if (k0 + 32 < K) {
#pragma unroll
      for (int c = 0; c < 2; ++c) {
        async_copy16(Ap[c] + k0 + 32, &As[nb][(c * 256 + t) * 8]);
        async_copy16(Bp[c] + k0 + 32, &Bs[nb][(c * 256 + t) * 8]);
      }
    }
    bf16x8 af[4], bfr[4];
#pragma unroll
    for (int i = 0; i < 4; ++i)
      af[i] = *(const bf16x8*)&As[buf][(wm + i * 16 + lr) * 32 + lq * 8];
#pragma unroll
    for (int j = 0; j < 4; ++j)
      bfr[j] = *(const bf16x8*)&Bs[buf][(wn + j * 16 + lr) * 32 + lq * 8];
#pragma unroll
    for (int i = 0; i < 4; ++i)
#pragma unroll
      for (int j = 0; j < 4; ++j)
        acc[i][j] = MFMA16(af[i], bfr[j], acc[i][j]);
    buf = nb;
  }
  if (z == 2) {
    // V transposed: vt[((b*16 + col/64)*64 + col%64)*2048 + n], quad = 4 n's
#pragma unroll
    for (int i = 0; i < 4; ++i) {
      const int row0 = bm + wm + i * 16 + lq * 4;  // n index base
      const int b = row0 >> 11;
      const int n = row0 & 2047;
#pragma unroll
      for (int j = 0; j < 4; ++j) {
        const int col = bn + wn + j * 16 + lr;  // global d (h*64 + dloc)
        bf16x4 pv;
#pragma unroll
        for (int r = 0; r < 4; ++r) pv[r] = (bf16_t)acc[i][j][r];
        *(bf16x4*)&vt[((size_t)(b * 16 + (col >> 6)) * 64 + (col & 63)) * 2048 + n] = pv;
      }
    }
  } else {
    bf16_t* Cb = (z == 0) ? C0 : C1;
#pragma unroll
    for (int i = 0; i < 4; ++i) {
      const int row = bm + wm + i * 16 + lq * 4;
#pragma unroll
      for (int j = 0; j < 4; ++j) {
        const int col = bn + wn + j * 16 + lr;
#pragma unroll
        for (int r = 0; r < 4; ++r)
          Cb[(size_t)(row + r) * Nn + col] = (bf16_t)(acc[i][j][r] * osc);
      }
    }
  }
}

// ---------------- flash attention v13: 8-wave blocks, dbuf, fused norm -------
__global__ __launch_bounds__(512, 2) void flash_attn(const bf16_t* __restrict__ q,
                                                     const bf16_t* __restrict__ k,
                                                     const bf16_t* __restrict__ vt,
                                                     bf16_t* __restrict__ attn) {
  __shared__ alignas(16) bf16_t Ks[2][64 * 64];
  __shared__ alignas(16) bf16_t Vs[2][64 * 64];
  const int t = threadIdx.x;   // 0..511
  const int lane = t & 63;
  const int w = t >> 6;        // wave 0..7, owns q-rows w*16..w*16+15
  const int lr = lane & 15;
  const int lq = lane >> 4;
  const int qt = blockIdx.x;   // query tile 0..15 (128 wide)
  const int bh = blockIdx.y;   // b*16+h
  const int b = bh >> 4;
  const int h = bh & 15;
  const size_t rowbase = (size_t)b * 2048;
  const int hcol = h * 64;
  const bf16_t* vtp = vt + (size_t)bh * 64 * 2048;

  bf16x8 qf0, qf1;
  {
    size_t qrow = rowbase + qt * 128 + w * 16 + lr;
    const bf16_t* qp = q + qrow * 1024 + hcol + lq * 8;
    qf0 = *(const bf16x8*)qp;
    qf1 = *(const bf16x8*)(qp + 32);
  }
  f32x4 of[4] = {};
  float lsum = 0.0f;

  // one 16B chunk per thread per tile (512 thr x 16B = 8KB = one 64x64 tile)
  const int sr = t >> 3;            // row 0..63
  const int sc = (t & 7) ^ (sr & 7);  // pre-swizzled 8-elem slot

  {
    async_copy16(k + (rowbase + sr) * 1024 + hcol + sc * 8, &Ks[0][t * 8]);
    async_copy16(vtp + (size_t)sr * 2048 + sc * 8, &Vs[0][t * 8]);
  }
  int buf = 0;
  for (int i = 0; i < 32; ++i) {
    __syncthreads();
    const int nb = buf ^ 1;
    if (i + 1 < 32) {
      const int ktn = i + 1;
      async_copy16(k + (rowbase + ktn * 64 + sr) * 1024 + hcol + sc * 8,
                   &Ks[nb][t * 8]);
      async_copy16(vtp + (size_t)sr * 2048 + ktn * 64 + sc * 8, &Vs[nb][t * 8]);
    }
    // ---- QK^T: scv[s][r] = S[k=16s+4*lq+r][q = qt*128 + w*16 + lr] ----
    f32x4 scv[4];
    __builtin_amdgcn_s_setprio(1);
#pragma unroll
    for (int s = 0; s < 4; ++s) {
      const int r2 = s * 16 + lr;
      bf16x8 kf0 = *(const bf16x8*)&Ks[buf][r2 * 64 + ((lq) ^ (r2 & 7)) * 8];
      bf16x8 kf1 = *(const bf16x8*)&Ks[buf][r2 * 64 + ((4 + lq) ^ (r2 & 7)) * 8];
      f32x4 c = {};
      c = MFMA16(kf0, qf0, c);
      c = MFMA16(kf1, qf1, c);
      scv[s] = c;
    }
    __builtin_amdgcn_s_setprio(0);
    // ---- exp, row-sum, in-register transpose into B-fragments ----
    float e[4][4];
#pragma unroll
    for (int s = 0; s < 4; ++s)
#pragma unroll
      for (int r = 0; r < 4; ++r) {
        e[s][r] = EXP2F(scv[s][r]);
        lsum += e[s][r];
      }
    unsigned w0[4], w1[4];
#pragma unroll
    for (int s = 0; s < 4; ++s) {
      w0[s] = cvt_pk_bf16(e[s][0], e[s][1]);
      w1[s] = cvt_pk_bf16(e[s][2], e[s][3]);
    }
    bf16x8 pf[2];
#pragma unroll
    for (int half = 0; half < 2; ++half) {
      unsigned a0 = w0[2 * half], a1 = w0[2 * half + 1];
      unsigned b0 = w1[2 * half], b1 = w1[2 * half + 1];
      plane32_swap(a0, a1);
      plane16_swap(a0, a1);
      plane32_swap(b0, b1);
      plane16_swap(b0, b1);
      union {
        bf16x8 v;
        unsigned wd[4];
      } pu;
      pu.wd[0] = a0;
      pu.wd[1] = b0;
      pu.wd[2] = a1;
      pu.wd[3] = b1;
      pf[half] = pu.v;
    }
    // ---- PV: O^T[d][q] += V^T (A) x P (B) ----
    __builtin_amdgcn_s_setprio(1);
#pragma unroll
    for (int d = 0; d < 4; ++d) {
      const int rv = d * 16 + lr;
      bf16x8 vf0 = *(const bf16x8*)&Vs[buf][rv * 64 + ((lq) ^ (rv & 7)) * 8];
      bf16x8 vf1 = *(const bf16x8*)&Vs[buf][rv * 64 + ((4 + lq) ^ (rv & 7)) * 8];
      of[d] = MFMA16(vf0, pf[0], of[d]);
      of[d] = MFMA16(vf1, pf[1], of[d]);
    }
    __builtin_amdgcn_s_setprio(0);
    buf = nb;
  }
  // of[d][r] = O^T[dglob = d*16 + lq*4 + r][q = qt*128 + w*16 + lr]
  float l = lsum;
  l += __shfl_xor(l, 16);
  l += __shfl_xor(l, 32);
  const float inv = 1.0f / l;
  const size_t qrow = rowbase + qt * 128 + w * 16 + lr;
#pragma unroll
  for (int d = 0; d < 4; ++d) {
    bf16x4 pv;
#pragma unroll
    for (int r = 0; r < 4; ++r) pv[r] = (bf16_t)(of[d][r] * inv);
    *(bf16x4*)&attn[qrow * 1024 + hcol + d * 16 + lq * 4] = pv;
  }
}

extern "C" void kernel_launch(void* const* d_in, const int* in_sizes, int n_in,
                              void* d_out, int out_size, void* d_ws, size_t ws_size,
                              hipStream_t stream) {
  (void)in_sizes;
  (void)n_in;
  (void)out_size;
  (void)ws_size;
  const float* x = (const float*)d_in[0];
  const float* la1g = (const float*)d_in[1];
  const float* la1b = (const float*)d_in[2];
  const float* Wq = (const float*)d_in[3];
  const float* Wk = (const float*)d_in[4];
  const float* Wv = (const float*)d_in[5];
  const float* Wo = (const float*)d_in[6];
  const float* bo = (const float*)d_in[7];
  const float* la2g = (const float*)d_in[8];
  const float* la2b = (const float*)d_in[9];
  const float* W1 = (const float*)d_in[10];
  const float* b1 = (const float*)d_in[11];
  const float* W2 = (const float*)d_in[12];
  const float* b2 = (const float*)d_in[13];
  char* ws = (char*)d_ws;
  const size_t MB = (size_t)1 << 20;
  bf16_t* wq_b = (bf16_t*)(ws + 0 * MB);
  bf16_t* wk_b = (bf16_t*)(ws + 2 * MB);
  bf16_t* wv_b = (bf16_t*)(ws + 4 * MB);
  bf16_t* wo_b = (bf16_t*)(ws + 6 * MB);
  bf16_t* w1_b = (bf16_t*)(ws + 8 * MB);
  bf16_t* w2_b = (bf16_t*)(ws + 16 * MB);
  bf16_t* hbuf = (bf16_t*)(ws + 24 * MB);  // ln1 out, QKV input
  bf16_t* qb = (bf16_t*)(ws + 32 * MB);
  bf16_t* kb = (bf16_t*)(ws + 40 * MB);
  bf16_t* vt = (bf16_t*)(ws + 48 * MB);    // V written transposed by QKV
  bf16_t* attn = (bf16_t*)(ws + 56 * MB);
  float* outb = (float*)(ws + 64 * MB);    // 16 MB fp32
  bf16_t* h2 = (bf16_t*)(ws + 80 * MB);    // 8 MB
  bf16_t* m1 = (bf16_t*)(ws + 88 * MB);    // 32 MB (88-120)
  float* dout = (float*)d_out;

  cvt_ln<<<16384, 256, 0, stream>>>(Wq, Wk, Wv, Wo, W1, W2, wq_b, wk_b, wv_b,
                                    wo_b, w1_b, w2_b, x, la1g, la1b, hbuf);
  gemm_qkv<<<dim3(8, 32, 3), 256, 0, stream>>>(hbuf, wq_b, wk_b, wv_b, qb, kb, vt);
  flash_attn<<<dim3(16, 32), 512, 0, stream>>>(qb, kb, vt, attn);
  gemm64_bt<1><<<dim3(8, 64), 256, 0, stream>>>(attn, wo_b, outb, bo, x, 4096, 1024, 1024);
  ln_k<<<4096, 256, 0, stream>>>(outb, la2g, la2b, h2);
  gemm256<2><<<256, 512, 0, stream>>>(h2, w1_b, m1, b1, 4096, 1024);
  gemm_sk2<<<dim3(8, 32), 512, 0, stream>>>(m1, w2_b, b2, outb, dout);
}